// Round 5
// baseline (430.469 us; speedup 1.0000x reference)
//
#include <hip/hip_runtime.h>

constexpr int kNL = 16384, kND = 4096, kNM = 2048;
constexpr int kE = 262144;              // 2^18
constexpr int kFEAT = 256, kHID = 64, kOUTF = 128;
constexpr int kITEMS = 4096, kSIZE = 2048;
constexpr int kHB = 16;                 // histogram chunks per index array
constexpr int kZS = 128;                // z row stride (merged 2-type layout)

typedef unsigned short ushort_t;
typedef unsigned int uint_t;
typedef __attribute__((ext_vector_type(8))) short short8v;
typedef __attribute__((ext_vector_type(4))) float f32x4;

struct EdgePtrs { const int* p[12]; };
struct I6 { int v[6]; };

__device__ inline ushort_t f2bf(float f) {
  unsigned u = __builtin_bit_cast(unsigned, f);
  unsigned r = u + 0x7fffu + ((u >> 16) & 1u);
  return (ushort_t)(r >> 16);
}
__device__ inline float bf2f(ushort_t b) {
  unsigned u = ((unsigned)b) << 16;
  return __builtin_bit_cast(float, u);
}

// async global->LDS, 16 B per lane (global_load_lds_dwordx4)
__device__ __forceinline__ void gload16(const ushort_t* g, ushort_t* l) {
  __builtin_amdgcn_global_load_lds(
      (const __attribute__((address_space(1))) void*)g,
      (__attribute__((address_space(3))) void*)l, 16, 0, 0);
}

// ===== prep: all fp32->bf16 converts + transpose-converts in ONE launch ====
struct PJob { const float* in; ushort_t* out; int A; int B; int kind; int nblk; };
struct PJobs { PJob j[24]; int n; };

__global__ __launch_bounds__(256) void prep_kernel(PJobs jobs) {
  __shared__ float t[32][33];
  int b = blockIdx.x;
  int ji = 0;
  while (ji < jobs.n && b >= jobs.j[ji].nblk) { b -= jobs.j[ji].nblk; ++ji; }
  if (ji >= jobs.n) return;
  PJob jb = jobs.j[ji];
  if (jb.kind == 0) {                       // flat convert, A = n4
    int idx = b * 256 + threadIdx.x;
    if (idx >= jb.A) return;
    float4 v = ((const float4*)jb.in)[idx];
    ushort_t* o = jb.out + (size_t)idx * 4;
    o[0] = f2bf(v.x); o[1] = f2bf(v.y); o[2] = f2bf(v.z); o[3] = f2bf(v.w);
  } else {                                  // transpose: in [K][N] -> out [N][K]; A=K, B=N
    int K = jb.A, N = jb.B;
    int tpr = N >> 5;
    int n0 = (b % tpr) * 32, k0 = (b / tpr) * 32;
    int tx = threadIdx.x & 31, ty = threadIdx.x >> 5;
#pragma unroll
    for (int i = 0; i < 32; i += 8)
      t[ty + i][tx] = jb.in[(size_t)(k0 + ty + i) * N + n0 + tx];
    __syncthreads();
#pragma unroll
    for (int i = 0; i < 32; i += 8)
      jb.out[(size_t)(n0 + ty + i) * K + k0 + tx] = f2bf(t[tx][ty + i]);
  }
}

// ===== degree/CSR build (no global atomics) ================================
__global__ __launch_bounds__(256) void hist_kernel(EdgePtrs ep, uint_t* __restrict__ part) {
  __shared__ uint_t bins[16384];
  int k = blockIdx.x >> 4, chunk = blockIdx.x & (kHB - 1);
  for (int i = threadIdx.x; i < 16384; i += 256) bins[i] = 0;
  __syncthreads();
  const int* arr = ep.p[k];
  int base = chunk * (kE / kHB);
  for (int i = threadIdx.x; i < kE / kHB; i += 256)
    atomicAdd(&bins[arr[base + i]], 1u);
  __syncthreads();
  uint_t* o = part + ((size_t)blockIdx.x << 14);
  for (int i = threadIdx.x; i < 16384; i += 256) o[i] = bins[i];
}

__global__ void reduce_finalize_kernel(const uint_t* __restrict__ part,
                                       uint_t* __restrict__ cnts,
                                       float* __restrict__ degscale) {
  int idx = blockIdx.x * 256 + threadIdx.x;   // grid = 12*16384/256
  int k = idx >> 14, bin = idx & 16383;
  uint_t s = 0;
  for (int c = 0; c < kHB; ++c) s += part[((size_t)(k * kHB + c) << 14) + bin];
  cnts[idx] = s;
  degscale[idx] = rsqrtf((float)max(s, 1u));
}

__global__ __launch_bounds__(1024) void scan_kernel(const uint_t* __restrict__ cnts,
                                                    uint_t* __restrict__ rp_all,
                                                    I6 rpoff, I6 nd) {
  __shared__ uint_t sums[1024];
  int t = blockIdx.x;
  int n = nd.v[t];
  const uint_t* c = cnts + ((size_t)(2 * t + 1) << 14);
  uint_t* rp = rp_all + rpoff.v[t];
  int tid = threadIdx.x;
  int seg = n >> 10;
  uint_t s = 0;
  for (int j = 0; j < seg; ++j) s += c[tid * seg + j];
  sums[tid] = s;
  __syncthreads();
  for (int o = 1; o < 1024; o <<= 1) {
    uint_t v = (tid >= o) ? sums[tid - o] : 0u;
    __syncthreads();
    sums[tid] += v;
    __syncthreads();
  }
  uint_t run = sums[tid] - s;   // exclusive
  for (int j = 0; j < seg; ++j) { rp[tid * seg + j] = run; run += c[tid * seg + j]; }
  if (tid == 1023) rp[n] = run;
}

__global__ void chunkofs_kernel(const uint_t* __restrict__ part,
                                const uint_t* __restrict__ rp_all,
                                I6 rpoff, I6 nd, uint_t* __restrict__ ofs) {
  int idx = blockIdx.x * 256 + threadIdx.x;   // grid = 6*16384/256
  int t = idx >> 14, bin = idx & 16383;
  if (bin >= nd.v[t]) return;
  uint_t run = (rp_all + rpoff.v[t])[bin];
  for (int c = 0; c < kHB; ++c) {
    ofs[((size_t)(t * kHB + c) << 14) + bin] = run;
    run += part[((size_t)((2 * t + 1) * kHB + c) << 14) + bin];
  }
}

__global__ __launch_bounds__(256) void fill_kernel(EdgePtrs ep,
                                                   const uint_t* __restrict__ ofs,
                                                   uint_t* __restrict__ csr_all) {
  __shared__ uint_t cursor[16384];
  int t = blockIdx.x >> 4, chunk = blockIdx.x & (kHB - 1);
  const uint_t* o = ofs + ((size_t)(t * kHB + chunk) << 14);
  for (int i = threadIdx.x; i < 16384; i += 256) cursor[i] = o[i];
  __syncthreads();
  const int* srcp = ep.p[2 * t];
  const int* dstp = ep.p[2 * t + 1];
  int base = chunk * (kE / kHB);
  uint_t* csr = csr_all + (size_t)t * kE;
  for (int i = threadIdx.x; i < kE / kHB; i += 256) {
    int e = base + i;
    int d = dstp[e];
    uint_t pos = atomicAdd(&cursor[d], 1u);
    csr[pos] = (uint_t)srcp[e];
  }
}

// ===== generic bf16 MFMA GEMM, 128x128 tile, global_load_lds + dbuf ========
// out = act([Cin +] A @ Bt^T + bias); split-K mode when partOut != null.
__global__ __launch_bounds__(256) void gemm_bf16_kernel(
    const ushort_t* __restrict__ A, const ushort_t* __restrict__ Bt,
    const float* __restrict__ Cin, void* __restrict__ out, int outBf16,
    int M, int N, int K, int ldb,
    const float* __restrict__ bias, int act,
    int kChunk, float* __restrict__ partOut) {
  __shared__ ushort_t As[2][128 * 32];   // 2 x 8 KB
  __shared__ ushort_t Bs[2][128 * 32];
  int tid = threadIdx.x;
  int wave = tid >> 6, lane = tid & 63;
  int brow = blockIdx.y * 128, bcol = blockIdx.x * 128;
  int kStart = partOut ? blockIdx.z * kChunk : 0;
  int kLen = partOut ? kChunk : K;

  // staging map: thread tid covers tile bytes [tid*16) and [4096 + tid*16)
  int arow = tid >> 2;                 // 0..63
  int aslot = tid & 3;                 // 16B slot within 64B row
  const ushort_t* gA = A + (size_t)(brow + arow) * K + kStart + aslot * 8;
  const ushort_t* gB = Bt + (size_t)(bcol + arow) * ldb + kStart + aslot * 8;
  size_t sA64 = (size_t)64 * K;
  size_t sB64 = (size_t)64 * ldb;

  int fr = lane & 15, fq = lane >> 4;

  f32x4 acc[2][8] = {};

  // prologue: stage buffer 0
  gload16(gA, &As[0][tid * 8]);
  gload16(gA + sA64, &As[0][2048 + tid * 8]);
  gload16(gB, &Bs[0][tid * 8]);
  gload16(gB + sB64, &Bs[0][2048 + tid * 8]);
  __syncthreads();                      // vmcnt(0) drain + barrier

  int cur = 0;
  for (int k0 = 0; k0 < kLen; k0 += 32) {
    if (k0 + 32 < kLen) {               // issue next-tile async loads first
      int nx = cur ^ 1;
      gload16(gA + k0 + 32, &As[nx][tid * 8]);
      gload16(gA + sA64 + k0 + 32, &As[nx][2048 + tid * 8]);
      gload16(gB + k0 + 32, &Bs[nx][tid * 8]);
      gload16(gB + sB64 + k0 + 32, &Bs[nx][2048 + tid * 8]);
    }
    short8v af[2], bfr[8];
#pragma unroll
    for (int mi = 0; mi < 2; ++mi)
      af[mi] = *(const short8v*)(&As[cur][(wave * 32 + mi * 16 + fr) * 32 + fq * 8]);
#pragma unroll
    for (int ni = 0; ni < 8; ++ni)
      bfr[ni] = *(const short8v*)(&Bs[cur][(ni * 16 + fr) * 32 + fq * 8]);
#pragma unroll
    for (int mi = 0; mi < 2; ++mi)
#pragma unroll
      for (int ni = 0; ni < 8; ++ni)
        acc[mi][ni] = __builtin_amdgcn_mfma_f32_16x16x32_bf16(af[mi], bfr[ni], acc[mi][ni], 0, 0, 0);
    __syncthreads();                    // drains next-tile vmcnt AFTER compute
    cur ^= 1;
  }

  if (partOut) {
    float* o = partOut + (size_t)blockIdx.z * M * N;
#pragma unroll
    for (int mi = 0; mi < 2; ++mi)
#pragma unroll
      for (int ni = 0; ni < 8; ++ni)
#pragma unroll
        for (int r = 0; r < 4; ++r) {
          int row = brow + wave * 32 + mi * 16 + fq * 4 + r;
          int col = bcol + ni * 16 + fr;
          o[(size_t)row * N + col] = acc[mi][ni][r];
        }
    return;
  }
#pragma unroll
  for (int mi = 0; mi < 2; ++mi)
#pragma unroll
    for (int ni = 0; ni < 8; ++ni)
#pragma unroll
      for (int r = 0; r < 4; ++r) {
        int row = brow + wave * 32 + mi * 16 + fq * 4 + r;
        int col = bcol + ni * 16 + fr;
        float v = acc[mi][ni][r];
        if (Cin) v += Cin[(size_t)row * N + col];
        if (bias) v += bias[col];
        if (act == 1) v = fmaxf(v, 0.0f);
        else if (act == 2) v = 1.0f / (1.0f + expf(-v));
        if (outBf16) ((ushort_t*)out)[(size_t)row * N + col] = f2bf(v);
        else ((float*)out)[(size_t)row * N + col] = v;
      }
}

// ===== batched z GEMM: N=128, out = [rs0|rs1] .* (A @ Bt^T), bf16 ==========
struct ZDesc { const ushort_t* A; const ushort_t* Bt; ushort_t* out;
               const float* rs0; const float* rs1; int M; int K; };
struct ZDescs { ZDesc d[3]; };

__global__ __launch_bounds__(256) void zgemm_batched_kernel(ZDescs ds) {
  __shared__ ushort_t As[2][128 * 32];
  __shared__ ushort_t Bs[2][128 * 32];
  ZDesc de = ds.d[blockIdx.z];
  int brow = blockIdx.y * 128;
  if (brow >= de.M) return;
  int K = de.K;
  int tid = threadIdx.x;
  int wave = tid >> 6, lane = tid & 63;

  int arow = tid >> 2, aslot = tid & 3;
  const ushort_t* gA = de.A + (size_t)(brow + arow) * K + aslot * 8;
  const ushort_t* gB = de.Bt + (size_t)arow * K + aslot * 8;
  size_t s64 = (size_t)64 * K;

  int fr = lane & 15, fq = lane >> 4;
  f32x4 acc[2][8] = {};

  gload16(gA, &As[0][tid * 8]);
  gload16(gA + s64, &As[0][2048 + tid * 8]);
  gload16(gB, &Bs[0][tid * 8]);
  gload16(gB + s64, &Bs[0][2048 + tid * 8]);
  __syncthreads();

  int cur = 0;
  for (int k0 = 0; k0 < K; k0 += 32) {
    if (k0 + 32 < K) {
      int nx = cur ^ 1;
      gload16(gA + k0 + 32, &As[nx][tid * 8]);
      gload16(gA + s64 + k0 + 32, &As[nx][2048 + tid * 8]);
      gload16(gB + k0 + 32, &Bs[nx][tid * 8]);
      gload16(gB + s64 + k0 + 32, &Bs[nx][2048 + tid * 8]);
    }
    short8v af[2], bfr[8];
#pragma unroll
    for (int mi = 0; mi < 2; ++mi)
      af[mi] = *(const short8v*)(&As[cur][(wave * 32 + mi * 16 + fr) * 32 + fq * 8]);
#pragma unroll
    for (int ni = 0; ni < 8; ++ni)
      bfr[ni] = *(const short8v*)(&Bs[cur][(ni * 16 + fr) * 32 + fq * 8]);
#pragma unroll
    for (int mi = 0; mi < 2; ++mi)
#pragma unroll
      for (int ni = 0; ni < 8; ++ni)
        acc[mi][ni] = __builtin_amdgcn_mfma_f32_16x16x32_bf16(af[mi], bfr[ni], acc[mi][ni], 0, 0, 0);
    __syncthreads();
    cur ^= 1;
  }

#pragma unroll
  for (int mi = 0; mi < 2; ++mi)
#pragma unroll
    for (int ni = 0; ni < 8; ++ni) {
      const float* rs = (ni < 4) ? de.rs0 : de.rs1;
#pragma unroll
      for (int r = 0; r < 4; ++r) {
        int row = brow + wave * 32 + mi * 16 + fq * 4 + r;
        int col = ni * 16 + fr;
        de.out[(size_t)row * 128 + col] = f2bf(acc[mi][ni][r] * rs[row]);
      }
    }
}

// ===== batched CSR gather (width 64, z row stride 128) =====================
struct GDesc { const ushort_t* z0; const uint_t* rp0; const uint_t* cs0; const float* s0;
               const ushort_t* z1; const uint_t* rp1; const uint_t* cs1; const float* s1;
               const float* b0; const float* b1; ushort_t* out; int nd; };
struct GDescs { GDesc d[3]; };

__global__ __launch_bounds__(256) void gather_batched_kernel(GDescs ds) {
  GDesc de = ds.d[blockIdx.z];
  int d = blockIdx.x * 4 + (threadIdx.x >> 6);
  if (d >= de.nd) return;
  int c = threadIdx.x & 63;
  float acc;
  {
    uint_t e = de.rp0[d], ee = de.rp0[d + 1];
    float a0 = 0, a1 = 0, a2 = 0, a3 = 0;
    for (; e + 4 <= ee; e += 4) {
      uint_t s0 = de.cs0[e], s1 = de.cs0[e + 1], s2 = de.cs0[e + 2], s3 = de.cs0[e + 3];
      a0 += bf2f(de.z0[s0 * kZS + c]); a1 += bf2f(de.z0[s1 * kZS + c]);
      a2 += bf2f(de.z0[s2 * kZS + c]); a3 += bf2f(de.z0[s3 * kZS + c]);
    }
    for (; e < ee; ++e) a0 += bf2f(de.z0[de.cs0[e] * kZS + c]);
    acc = (a0 + a1 + a2 + a3) * de.s0[d];
  }
  {
    uint_t e = de.rp1[d], ee = de.rp1[d + 1];
    float a0 = 0, a1 = 0, a2 = 0, a3 = 0;
    for (; e + 4 <= ee; e += 4) {
      uint_t s0 = de.cs1[e], s1 = de.cs1[e + 1], s2 = de.cs1[e + 2], s3 = de.cs1[e + 3];
      a0 += bf2f(de.z1[s0 * kZS + c]); a1 += bf2f(de.z1[s1 * kZS + c]);
      a2 += bf2f(de.z1[s2 * kZS + c]); a3 += bf2f(de.z1[s3 * kZS + c]);
    }
    for (; e < ee; ++e) a0 += bf2f(de.z1[de.cs1[e] * kZS + c]);
    acc += (a0 + a1 + a2 + a3) * de.s1[d];
  }
  acc += de.b0[c] + de.b1[c];
  de.out[(size_t)d * 64 + c] = f2bf(acc);
}

// ===== layer-3 gather (width 128, d<2048) fused with L1 normalize ==========
__global__ __launch_bounds__(256) void gather128_l1_kernel(
    const ushort_t* __restrict__ zD, const uint_t* __restrict__ rpD, const uint_t* __restrict__ csD,
    const float* __restrict__ sInD,
    const ushort_t* __restrict__ zM, const uint_t* __restrict__ rpM, const uint_t* __restrict__ csM,
    const float* __restrict__ sInM,
    const float* __restrict__ bD, const float* __restrict__ bM,
    float* __restrict__ emb, ushort_t* __restrict__ embb) {
  int d = blockIdx.x * 4 + (threadIdx.x >> 6);
  int c = threadIdx.x & 63;
  float v0 = 0, v1 = 0;
  {
    uint_t e = rpD[d], ee = rpD[d + 1];
    float a0 = 0, a1 = 0, h0 = 0, h1 = 0;
    for (; e + 2 <= ee; e += 2) {
      uint_t s0 = csD[e], s1 = csD[e + 1];
      a0 += bf2f(zD[s0 * 128 + c]);      h0 += bf2f(zD[s0 * 128 + 64 + c]);
      a1 += bf2f(zD[s1 * 128 + c]);      h1 += bf2f(zD[s1 * 128 + 64 + c]);
    }
    if (e < ee) { uint_t s = csD[e]; a0 += bf2f(zD[s * 128 + c]); h0 += bf2f(zD[s * 128 + 64 + c]); }
    v0 += (a0 + a1) * sInD[d]; v1 += (h0 + h1) * sInD[d];
  }
  {
    uint_t e = rpM[d], ee = rpM[d + 1];
    float a0 = 0, a1 = 0, h0 = 0, h1 = 0;
    for (; e + 2 <= ee; e += 2) {
      uint_t s0 = csM[e], s1 = csM[e + 1];
      a0 += bf2f(zM[s0 * 128 + c]);      h0 += bf2f(zM[s0 * 128 + 64 + c]);
      a1 += bf2f(zM[s1 * 128 + c]);      h1 += bf2f(zM[s1 * 128 + 64 + c]);
    }
    if (e < ee) { uint_t s = csM[e]; a0 += bf2f(zM[s * 128 + c]); h0 += bf2f(zM[s * 128 + 64 + c]); }
    v0 += (a0 + a1) * sInM[d]; v1 += (h0 + h1) * sInM[d];
  }
  v0 += bD[c] + bM[c];
  v1 += bD[64 + c] + bM[64 + c];
  float a = fabsf(v0) + fabsf(v1);
#pragma unroll
  for (int o = 32; o > 0; o >>= 1) a += __shfl_xor(a, o);
  float l1 = fmaxf(a, 1e-12f);
  float e0 = v0 / l1, e1 = v1 / l1;
  emb[d * kOUTF + c] = e0;
  emb[d * kOUTF + 64 + c] = e1;
  embb[d * kOUTF + c] = f2bf(e0);
  embb[d * kOUTF + 64 + c] = f2bf(e1);
}

// ===== split-K reduce ======================================================
__global__ void reducek_kernel(const float* __restrict__ P, float* __restrict__ out,
                               int n4, int S) {
  int idx = blockIdx.x * 256 + threadIdx.x;
  if (idx >= n4) return;
  float4 a = ((const float4*)P)[idx];
  for (int s = 1; s < S; ++s) {
    float4 b = ((const float4*)P)[(size_t)s * n4 + idx];
    a.x += b.x; a.y += b.y; a.z += b.z; a.w += b.w;
  }
  ((float4*)out)[idx] = a;
}

extern "C" void kernel_launch(void* const* d_in, const int* in_sizes, int n_in,
                              void* d_out, int out_size, void* d_ws, size_t ws_size,
                              hipStream_t stream) {
  const float* h_L = (const float*)d_in[0];
  const float* h_D = (const float*)d_in[1];
  const float* h_M = (const float*)d_in[2];
  const float* Adj = (const float*)d_in[3];
  EdgePtrs ep;
  for (int i = 0; i < 12; ++i) ep.p[i] = (const int*)d_in[4 + i];
  const float* W[3]  = {(const float*)d_in[16], (const float*)d_in[18], (const float*)d_in[20]};
  const float* Bb[3] = {(const float*)d_in[17], (const float*)d_in[19], (const float*)d_in[21]};
  const float* f1_w = (const float*)d_in[22];
  const float* f1_b = (const float*)d_in[23];
  const float* f2_w = (const float*)d_in[24];
  const float* f2_b = (const float*)d_in[25];
  const float* f3_w = (const float*)d_in[26];
  const float* f3_b = (const float*)d_in[27];
  const float* f4_w = (const float*)d_in[28];
  const float* f4_b = (const float*)d_in[29];

  // ---- workspace layout ----
  float* ws = (float*)d_ws;
  size_t off = 0;
  auto allocF = [&](size_t n) { float* p = ws + off; off += (n + 3) & ~(size_t)3; return p; };
  auto allocU = [&](size_t n) { return (uint_t*)allocF(n); };
  auto allocB = [&](size_t n) { return (ushort_t*)allocF((n + 1) / 2); };

  uint_t* part   = allocU((size_t)12 * kHB * 16384);   // 12.6 MB, reused as z bufs
  uint_t* cnts   = allocU((size_t)12 * 16384);
  float*  degscale = allocF((size_t)12 * 16384);
  uint_t* rp_all = allocU(45062 + 2);
  uint_t* ofs    = allocU((size_t)6 * kHB * 16384);
  uint_t* csr    = allocU((size_t)6 * kE);
  float* x1f   = allocF((size_t)kSIZE * 256);
  ushort_t* hLb  = allocB((size_t)kNL * kFEAT);
  ushort_t* hDb  = allocB((size_t)kND * kFEAT);
  ushort_t* hMb  = allocB((size_t)kNM * kFEAT);
  ushort_t* Adjb = allocB((size_t)kSIZE * kITEMS);
  ushort_t* aLb  = allocB((size_t)kNL * kHID);
  ushort_t* aDb  = allocB((size_t)kND * kHID);
  ushort_t* aMb  = allocB((size_t)kNM * kHID);
  ushort_t* WLt  = allocB((size_t)128 * kFEAT);   // layer1 [W0;W2]^T
  ushort_t* WDt  = allocB((size_t)128 * kFEAT);   // [W1;W4]^T
  ushort_t* WMt  = allocB((size_t)128 * kFEAT);   // [W3;W5]^T
  ushort_t* WL2t = allocB((size_t)128 * kHID);
  ushort_t* WD2t = allocB((size_t)128 * kHID);
  ushort_t* WM2t = allocB((size_t)128 * kHID);
  ushort_t* W3t1 = allocB((size_t)kOUTF * kHID);
  ushort_t* W3t3 = allocB((size_t)kOUTF * kHID);
  ushort_t* f1t  = allocB((size_t)256 * (kITEMS + kOUTF));
  ushort_t* f2t  = allocB((size_t)512 * 256);
  ushort_t* f3t  = allocB((size_t)1024 * 512);
  ushort_t* f4t  = allocB((size_t)kITEMS * 1024);
  ushort_t* embb = allocB((size_t)kSIZE * kOUTF);
  ushort_t* x1b  = allocB((size_t)kSIZE * 256);
  ushort_t* x2b  = allocB((size_t)kSIZE * 512);
  ushort_t* x3b  = allocB((size_t)kSIZE * 1024);

  // split-K partials if workspace allows
  int S = 1;
  float* partK = x1f;
  if ((off + (size_t)8 * kSIZE * 256 + 16) * 4 <= ws_size) {
    S = 8;
    partK = allocF((size_t)8 * kSIZE * 256);
  }

  // z buffers alias `part` (dead after chunkofs/fill)
  ushort_t* zL  = (ushort_t*)part;                       // 16384 x 128
  ushort_t* zD  = zL + (size_t)kNL * kZS;                // 4096 x 128
  ushort_t* zM  = zD + (size_t)kND * kZS;                // 2048 x 128
  ushort_t* zD3 = zM + (size_t)kNM * kZS;                // 4096 x 128
  ushort_t* zM3 = zD3 + (size_t)kND * kZS;               // 2048 x 128

  I6 ndI; const int ndst_[6] = {kND, kNL, kNM, kNL, kNM, kND};
  for (int t = 0; t < 6; ++t) ndI.v[t] = ndst_[t];
  I6 rpo; { int r = 0; for (int t = 0; t < 6; ++t) { rpo.v[t] = r; r += ndst_[t] + 1; } }
  auto dsc = [&](int k) { return degscale + ((size_t)k << 14); };

  // ---- 1) one prep launch: converts + all weight transposes ----
  PJobs pj; int nj = 0; int totblk = 0;
  auto addCvt = [&](const float* in, ushort_t* out, size_t n) {
    int n4 = (int)(n / 4);
    pj.j[nj] = {in, out, n4, 0, 0, (n4 + 255) / 256}; totblk += pj.j[nj].nblk; ++nj;
  };
  auto addT = [&](const float* in, ushort_t* out, int K, int N) {
    pj.j[nj] = {in, out, K, N, 1, (N / 32) * (K / 32)}; totblk += pj.j[nj].nblk; ++nj;
  };
  addCvt(h_L, hLb, (size_t)kNL * kFEAT);
  addCvt(h_D, hDb, (size_t)kND * kFEAT);
  addCvt(h_M, hMb, (size_t)kNM * kFEAT);
  addCvt(Adj, Adjb, (size_t)kSIZE * kITEMS);
  // layer1 merged weights (K=256, each slice 64 rows)
  addT(W[0] + (size_t)0 * kFEAT * kHID, WLt + (size_t)0 * kFEAT, kFEAT, kHID);
  addT(W[0] + (size_t)2 * kFEAT * kHID, WLt + (size_t)64 * kFEAT, kFEAT, kHID);
  addT(W[0] + (size_t)1 * kFEAT * kHID, WDt + (size_t)0 * kFEAT, kFEAT, kHID);
  addT(W[0] + (size_t)4 * kFEAT * kHID, WDt + (size_t)64 * kFEAT, kFEAT, kHID);
  addT(W[0] + (size_t)3 * kFEAT * kHID, WMt + (size_t)0 * kFEAT, kFEAT, kHID);
  addT(W[0] + (size_t)5 * kFEAT * kHID, WMt + (size_t)64 * kFEAT, kFEAT, kHID);
  // layer2 merged weights (K=64)
  addT(W[1] + (size_t)0 * kHID * kHID, WL2t + (size_t)0 * kHID, kHID, kHID);
  addT(W[1] + (size_t)2 * kHID * kHID, WL2t + (size_t)64 * kHID, kHID, kHID);
  addT(W[1] + (size_t)1 * kHID * kHID, WD2t + (size_t)0 * kHID, kHID, kHID);
  addT(W[1] + (size_t)4 * kHID * kHID, WD2t + (size_t)64 * kHID, kHID, kHID);
  addT(W[1] + (size_t)3 * kHID * kHID, WM2t + (size_t)0 * kHID, kHID, kHID);
  addT(W[1] + (size_t)5 * kHID * kHID, WM2t + (size_t)64 * kHID, kHID, kHID);
  // layer3: only types 1, 3 (N=128)
  addT(W[2] + (size_t)1 * kHID * kOUTF, W3t1, kHID, kOUTF);
  addT(W[2] + (size_t)3 * kHID * kOUTF, W3t3, kHID, kOUTF);
  // MLP weights
  addT(f1_w, f1t, kITEMS + kOUTF, 256);
  addT(f2_w, f2t, 256, 512);
  addT(f3_w, f3t, 512, 1024);
  addT(f4_w, f4t, 1024, kITEMS);
  pj.n = nj;
  prep_kernel<<<totblk, 256, 0, stream>>>(pj);

  // ---- 2) degree + CSR build ----
  hist_kernel<<<12 * kHB, 256, 0, stream>>>(ep, part);
  reduce_finalize_kernel<<<12 * 16384 / 256, 256, 0, stream>>>(part, cnts, degscale);
  scan_kernel<<<6, 1024, 0, stream>>>(cnts, rp_all, rpo, ndI);
  chunkofs_kernel<<<6 * 16384 / 256, 256, 0, stream>>>(part, rp_all, rpo, ndI, ofs);
  fill_kernel<<<6 * kHB, 256, 0, stream>>>(ep, ofs, csr);

  // ---- 3) Adj @ f1_w[:4096] with split-K ----
  gemm_bf16_kernel<<<dim3(2, 16, S), 256, 0, stream>>>(
      Adjb, f1t, nullptr, nullptr, 0, kSIZE, 256, kITEMS, kITEMS + kOUTF,
      nullptr, 0, kITEMS / S, partK);
  if (S > 1)
    reducek_kernel<<<kSIZE * 256 / 4 / 256, 256, 0, stream>>>(partK, x1f, kSIZE * 256 / 4, S);

  // ---- 4) GNN layers 1 & 2 ----
  const ushort_t* curb[3] = {hLb, hDb, hMb};
  for (int layer = 0; layer < 2; ++layer) {
    int K = (layer == 0) ? kFEAT : kHID;
    const ushort_t* WtL = (layer == 0) ? WLt : WL2t;
    const ushort_t* WtD = (layer == 0) ? WDt : WD2t;
    const ushort_t* WtM = (layer == 0) ? WMt : WM2t;
    const float* bl = Bb[layer];
    ZDescs zd;
    zd.d[0] = {curb[0], WtL, zL, dsc(0), dsc(4),  kNL, K};
    zd.d[1] = {curb[1], WtD, zD, dsc(2), dsc(8),  kND, K};
    zd.d[2] = {curb[2], WtM, zM, dsc(6), dsc(10), kNM, K};
    zgemm_batched_kernel<<<dim3(1, kNL / 128, 3), 256, 0, stream>>>(zd);
    GDescs gd;
    // oL <- t1 (zD cols 0-63) + t3 (zM cols 0-63)
    gd.d[0] = {zD, rp_all + rpo.v[1], csr + (size_t)1 * kE, dsc(3),
               zM, rp_all + rpo.v[3], csr + (size_t)3 * kE, dsc(7),
               bl + 1 * kHID, bl + 3 * kHID, aLb, kNL};
    // oD <- t0 (zL cols 0-63) + t5 (zM cols 64-127)
    gd.d[1] = {zL, rp_all + rpo.v[0], csr + (size_t)0 * kE, dsc(1),
               zM + 64, rp_all + rpo.v[5], csr + (size_t)5 * kE, dsc(11),
               bl + 0 * kHID, bl + 5 * kHID, aDb, kND};
    // oM <- t2 (zL cols 64-127) + t4 (zD cols 64-127)
    gd.d[2] = {zL + 64, rp_all + rpo.v[2], csr + (size_t)2 * kE, dsc(5),
               zD + 64, rp_all + rpo.v[4], csr + (size_t)4 * kE, dsc(9),
               bl + 2 * kHID, bl + 4 * kHID, aMb, kNM};
    gather_batched_kernel<<<dim3(kNL / 4, 1, 3), 256, 0, stream>>>(gd);
    curb[0] = aLb; curb[1] = aDb; curb[2] = aMb;
  }

  // ---- 5) layer 3 (types 1: D->L, 3: M->L; rows < 2048) + L1 norm ----
  float* emb  = (float*)d_out;
  float* outx = (float*)d_out + (size_t)kSIZE * kOUTF;
  {
    ZDescs zd;
    zd.d[0] = {curb[1], W3t1, zD3, dsc(2), dsc(2), kND, kHID};
    zd.d[1] = {curb[2], W3t3, zM3, dsc(6), dsc(6), kNM, kHID};
    zd.d[2] = zd.d[1];
    zgemm_batched_kernel<<<dim3(1, kND / 128, 2), 256, 0, stream>>>(zd);
    gather128_l1_kernel<<<kSIZE / 4, 256, 0, stream>>>(
        zD3, rp_all + rpo.v[1], csr + (size_t)1 * kE, dsc(3),
        zM3, rp_all + rpo.v[3], csr + (size_t)3 * kE, dsc(7),
        Bb[2] + 1 * kOUTF, Bb[2] + 3 * kOUTF, emb, embb);
  }

  // ---- 6) MLP ----
  gemm_bf16_kernel<<<dim3(2, 16, 1), 256, 0, stream>>>(
      embb, f1t + kITEMS, x1f, x1b, 1, kSIZE, 256, kOUTF, kITEMS + kOUTF,
      f1_b, 1, 0, nullptr);
  gemm_bf16_kernel<<<dim3(4, 16, 1), 256, 0, stream>>>(
      x1b, f2t, nullptr, x2b, 1, kSIZE, 512, 256, 256, f2_b, 1, 0, nullptr);
  gemm_bf16_kernel<<<dim3(8, 16, 1), 256, 0, stream>>>(
      x2b, f3t, nullptr, x3b, 1, kSIZE, 1024, 512, 512, f3_b, 1, 0, nullptr);
  gemm_bf16_kernel<<<dim3(32, 16, 1), 256, 0, stream>>>(
      x3b, f4t, nullptr, outx, 0, kSIZE, kITEMS, 1024, 1024, f4_b, 2, 0, nullptr);
}

// Round 6
// 427.562 us; speedup vs baseline: 1.0068x; 1.0068x over previous
//
#include <hip/hip_runtime.h>

constexpr int kNL = 16384, kND = 4096, kNM = 2048;
constexpr int kE = 262144;              // 2^18
constexpr int kFEAT = 256, kHID = 64, kOUTF = 128;
constexpr int kITEMS = 4096, kSIZE = 2048;
constexpr int kHB = 16;                 // histogram chunks per index array
constexpr int kZS = 128;                // z row stride (merged 2-type layout)

typedef unsigned short ushort_t;
typedef unsigned int uint_t;
typedef __attribute__((ext_vector_type(8))) short short8v;
typedef __attribute__((ext_vector_type(4))) float f32x4;

struct EdgePtrs { const int* p[12]; };
struct I6 { int v[6]; };

__device__ inline ushort_t f2bf(float f) {
  unsigned u = __builtin_bit_cast(unsigned, f);
  unsigned r = u + 0x7fffu + ((u >> 16) & 1u);
  return (ushort_t)(r >> 16);
}
__device__ inline float bf2f(ushort_t b) {
  unsigned u = ((unsigned)b) << 16;
  return __builtin_bit_cast(float, u);
}

// async global->LDS, 16 B per lane (global_load_lds_dwordx4)
__device__ __forceinline__ void gload16(const ushort_t* g, ushort_t* l) {
  __builtin_amdgcn_global_load_lds(
      (const __attribute__((address_space(1))) void*)g,
      (__attribute__((address_space(3))) void*)l, 16, 0, 0);
}

// ===== prep: all fp32->bf16 converts + transpose-converts in ONE launch ====
struct PJob { const float* in; ushort_t* out; int A; int B; int kind; int nblk; };
struct PJobs { PJob j[24]; int n; };

__global__ __launch_bounds__(256) void prep_kernel(PJobs jobs) {
  __shared__ float t[32][33];
  int b = blockIdx.x;
  int ji = 0;
  while (ji < jobs.n && b >= jobs.j[ji].nblk) { b -= jobs.j[ji].nblk; ++ji; }
  if (ji >= jobs.n) return;
  PJob jb = jobs.j[ji];
  if (jb.kind == 0) {                       // flat convert, A = n4
    int idx = b * 256 + threadIdx.x;
    if (idx >= jb.A) return;
    float4 v = ((const float4*)jb.in)[idx];
    ushort_t* o = jb.out + (size_t)idx * 4;
    o[0] = f2bf(v.x); o[1] = f2bf(v.y); o[2] = f2bf(v.z); o[3] = f2bf(v.w);
  } else {                                  // transpose: in [K][N] -> out [N][K]; A=K, B=N
    int K = jb.A, N = jb.B;
    int tpr = N >> 5;
    int n0 = (b % tpr) * 32, k0 = (b / tpr) * 32;
    int tx = threadIdx.x & 31, ty = threadIdx.x >> 5;
#pragma unroll
    for (int i = 0; i < 32; i += 8)
      t[ty + i][tx] = jb.in[(size_t)(k0 + ty + i) * N + n0 + tx];
    __syncthreads();
#pragma unroll
    for (int i = 0; i < 32; i += 8)
      jb.out[(size_t)(n0 + ty + i) * K + k0 + tx] = f2bf(t[tx][ty + i]);
  }
}

// ===== degree/CSR build (no global atomics) ================================
__global__ __launch_bounds__(256) void hist_kernel(EdgePtrs ep, uint_t* __restrict__ part) {
  __shared__ uint_t bins[16384];
  int k = blockIdx.x >> 4, chunk = blockIdx.x & (kHB - 1);
  for (int i = threadIdx.x; i < 16384; i += 256) bins[i] = 0;
  __syncthreads();
  const int* arr = ep.p[k];
  int base = chunk * (kE / kHB);
  for (int i = threadIdx.x; i < kE / kHB; i += 256)
    atomicAdd(&bins[arr[base + i]], 1u);
  __syncthreads();
  uint_t* o = part + ((size_t)blockIdx.x << 14);
  for (int i = threadIdx.x; i < 16384; i += 256) o[i] = bins[i];
}

__global__ void reduce_finalize_kernel(const uint_t* __restrict__ part,
                                       uint_t* __restrict__ cnts,
                                       float* __restrict__ degscale) {
  int idx = blockIdx.x * 256 + threadIdx.x;   // grid = 12*16384/256
  int k = idx >> 14, bin = idx & 16383;
  uint_t s = 0;
  for (int c = 0; c < kHB; ++c) s += part[((size_t)(k * kHB + c) << 14) + bin];
  cnts[idx] = s;
  degscale[idx] = rsqrtf((float)max(s, 1u));
}

__global__ __launch_bounds__(1024) void scan_kernel(const uint_t* __restrict__ cnts,
                                                    uint_t* __restrict__ rp_all,
                                                    I6 rpoff, I6 nd) {
  __shared__ uint_t sums[1024];
  int t = blockIdx.x;
  int n = nd.v[t];
  const uint_t* c = cnts + ((size_t)(2 * t + 1) << 14);
  uint_t* rp = rp_all + rpoff.v[t];
  int tid = threadIdx.x;
  int seg = n >> 10;
  uint_t s = 0;
  for (int j = 0; j < seg; ++j) s += c[tid * seg + j];
  sums[tid] = s;
  __syncthreads();
  for (int o = 1; o < 1024; o <<= 1) {
    uint_t v = (tid >= o) ? sums[tid - o] : 0u;
    __syncthreads();
    sums[tid] += v;
    __syncthreads();
  }
  uint_t run = sums[tid] - s;   // exclusive
  for (int j = 0; j < seg; ++j) { rp[tid * seg + j] = run; run += c[tid * seg + j]; }
  if (tid == 1023) rp[n] = run;
}

__global__ void chunkofs_kernel(const uint_t* __restrict__ part,
                                const uint_t* __restrict__ rp_all,
                                I6 rpoff, I6 nd, uint_t* __restrict__ ofs) {
  int idx = blockIdx.x * 256 + threadIdx.x;   // grid = 6*16384/256
  int t = idx >> 14, bin = idx & 16383;
  if (bin >= nd.v[t]) return;
  uint_t run = (rp_all + rpoff.v[t])[bin];
  for (int c = 0; c < kHB; ++c) {
    ofs[((size_t)(t * kHB + c) << 14) + bin] = run;
    run += part[((size_t)((2 * t + 1) * kHB + c) << 14) + bin];
  }
}

__global__ __launch_bounds__(256) void fill_kernel(EdgePtrs ep,
                                                   const uint_t* __restrict__ ofs,
                                                   uint_t* __restrict__ csr_all) {
  __shared__ uint_t cursor[16384];
  int t = blockIdx.x >> 4, chunk = blockIdx.x & (kHB - 1);
  const uint_t* o = ofs + ((size_t)(t * kHB + chunk) << 14);
  for (int i = threadIdx.x; i < 16384; i += 256) cursor[i] = o[i];
  __syncthreads();
  const int* srcp = ep.p[2 * t];
  const int* dstp = ep.p[2 * t + 1];
  int base = chunk * (kE / kHB);
  uint_t* csr = csr_all + (size_t)t * kE;
  for (int i = threadIdx.x; i < kE / kHB; i += 256) {
    int e = base + i;
    int d = dstp[e];
    uint_t pos = atomicAdd(&cursor[d], 1u);
    csr[pos] = (uint_t)srcp[e];
  }
}

// ===== generic bf16 MFMA GEMM, 128x128 tile ================================
// global_load_lds staging with PRE-SWIZZLED global source (rule #21):
// LDS dest linear; lane's global slot = (aslot ^ sw(row)); fragment read
// applies the same XOR -> conflict-free ds_read_b128 (2-way only).
__global__ __launch_bounds__(256) void gemm_bf16_kernel(
    const ushort_t* __restrict__ A, const ushort_t* __restrict__ Bt,
    const float* __restrict__ Cin, void* __restrict__ out, int outBf16,
    int M, int N, int K, int ldb,
    const float* __restrict__ bias, int act,
    int kChunk, float* __restrict__ partOut) {
  __shared__ ushort_t As[2][128 * 32];   // 2 x 8 KB
  __shared__ ushort_t Bs[2][128 * 32];
  int tid = threadIdx.x;
  int wave = tid >> 6, lane = tid & 63;
  int brow = blockIdx.y * 128, bcol = blockIdx.x * 128;
  int kStart = partOut ? blockIdx.z * kChunk : 0;
  int kLen = partOut ? kChunk : K;

  // staging map: LDS linear; global slot pre-swizzled within 64B row
  int arow = tid >> 2;                 // 0..63 (and +64 for second half)
  int aslot = tid & 3;                 // 16B slot within 64B row
  int sw = (arow >> 1) & 3;            // same for row and row+64
  const ushort_t* gA = A + (size_t)(brow + arow) * K + kStart + (aslot ^ sw) * 8;
  const ushort_t* gB = Bt + (size_t)(bcol + arow) * ldb + kStart + (aslot ^ sw) * 8;
  size_t sA64 = (size_t)64 * K;
  size_t sB64 = (size_t)64 * ldb;

  int fr = lane & 15, fq = lane >> 4;

  f32x4 acc[2][8] = {};

  // prologue: stage buffer 0
  gload16(gA, &As[0][tid * 8]);
  gload16(gA + sA64, &As[0][2048 + tid * 8]);
  gload16(gB, &Bs[0][tid * 8]);
  gload16(gB + sB64, &Bs[0][2048 + tid * 8]);
  __syncthreads();                      // vmcnt(0) drain + barrier

  int cur = 0;
  for (int k0 = 0; k0 < kLen; k0 += 32) {
    if (k0 + 32 < kLen) {               // issue next-tile async loads first
      int nx = cur ^ 1;
      gload16(gA + k0 + 32, &As[nx][tid * 8]);
      gload16(gA + sA64 + k0 + 32, &As[nx][2048 + tid * 8]);
      gload16(gB + k0 + 32, &Bs[nx][tid * 8]);
      gload16(gB + sB64 + k0 + 32, &Bs[nx][2048 + tid * 8]);
    }
    short8v af[2], bfr[8];
#pragma unroll
    for (int mi = 0; mi < 2; ++mi) {
      int row = wave * 32 + mi * 16 + fr;
      af[mi] = *(const short8v*)(&As[cur][row * 32 + ((fq ^ ((row >> 1) & 3)) * 8)]);
    }
#pragma unroll
    for (int ni = 0; ni < 8; ++ni) {
      int row = ni * 16 + fr;
      bfr[ni] = *(const short8v*)(&Bs[cur][row * 32 + ((fq ^ ((row >> 1) & 3)) * 8)]);
    }
#pragma unroll
    for (int mi = 0; mi < 2; ++mi)
#pragma unroll
      for (int ni = 0; ni < 8; ++ni)
        acc[mi][ni] = __builtin_amdgcn_mfma_f32_16x16x32_bf16(af[mi], bfr[ni], acc[mi][ni], 0, 0, 0);
    __syncthreads();                    // drains next-tile vmcnt AFTER compute
    cur ^= 1;
  }

  if (partOut) {
    float* o = partOut + (size_t)blockIdx.z * M * N;
#pragma unroll
    for (int mi = 0; mi < 2; ++mi)
#pragma unroll
      for (int ni = 0; ni < 8; ++ni)
#pragma unroll
        for (int r = 0; r < 4; ++r) {
          int row = brow + wave * 32 + mi * 16 + fq * 4 + r;
          int col = bcol + ni * 16 + fr;
          o[(size_t)row * N + col] = acc[mi][ni][r];
        }
    return;
  }
#pragma unroll
  for (int mi = 0; mi < 2; ++mi)
#pragma unroll
    for (int ni = 0; ni < 8; ++ni)
#pragma unroll
      for (int r = 0; r < 4; ++r) {
        int row = brow + wave * 32 + mi * 16 + fq * 4 + r;
        int col = bcol + ni * 16 + fr;
        float v = acc[mi][ni][r];
        if (Cin) v += Cin[(size_t)row * N + col];
        if (bias) v += bias[col];
        if (act == 1) v = fmaxf(v, 0.0f);
        else if (act == 2) v = 1.0f / (1.0f + expf(-v));
        if (outBf16) ((ushort_t*)out)[(size_t)row * N + col] = f2bf(v);
        else ((float*)out)[(size_t)row * N + col] = v;
      }
}

// ===== batched z GEMM: N=128, out = [rs0|rs1] .* (A @ Bt^T), bf16 ==========
struct ZDesc { const ushort_t* A; const ushort_t* Bt; ushort_t* out;
               const float* rs0; const float* rs1; int M; int K; };
struct ZDescs { ZDesc d[3]; };

__global__ __launch_bounds__(256) void zgemm_batched_kernel(ZDescs ds) {
  __shared__ ushort_t As[2][128 * 32];
  __shared__ ushort_t Bs[2][128 * 32];
  ZDesc de = ds.d[blockIdx.z];
  int brow = blockIdx.y * 128;
  if (brow >= de.M) return;
  int K = de.K;
  int tid = threadIdx.x;
  int wave = tid >> 6, lane = tid & 63;

  int arow = tid >> 2, aslot = tid & 3;
  int sw = (arow >> 1) & 3;
  const ushort_t* gA = de.A + (size_t)(brow + arow) * K + (aslot ^ sw) * 8;
  const ushort_t* gB = de.Bt + (size_t)arow * K + (aslot ^ sw) * 8;
  size_t s64 = (size_t)64 * K;

  int fr = lane & 15, fq = lane >> 4;
  f32x4 acc[2][8] = {};

  gload16(gA, &As[0][tid * 8]);
  gload16(gA + s64, &As[0][2048 + tid * 8]);
  gload16(gB, &Bs[0][tid * 8]);
  gload16(gB + s64, &Bs[0][2048 + tid * 8]);
  __syncthreads();

  int cur = 0;
  for (int k0 = 0; k0 < K; k0 += 32) {
    if (k0 + 32 < K) {
      int nx = cur ^ 1;
      gload16(gA + k0 + 32, &As[nx][tid * 8]);
      gload16(gA + s64 + k0 + 32, &As[nx][2048 + tid * 8]);
      gload16(gB + k0 + 32, &Bs[nx][tid * 8]);
      gload16(gB + s64 + k0 + 32, &Bs[nx][2048 + tid * 8]);
    }
    short8v af[2], bfr[8];
#pragma unroll
    for (int mi = 0; mi < 2; ++mi) {
      int row = wave * 32 + mi * 16 + fr;
      af[mi] = *(const short8v*)(&As[cur][row * 32 + ((fq ^ ((row >> 1) & 3)) * 8)]);
    }
#pragma unroll
    for (int ni = 0; ni < 8; ++ni) {
      int row = ni * 16 + fr;
      bfr[ni] = *(const short8v*)(&Bs[cur][row * 32 + ((fq ^ ((row >> 1) & 3)) * 8)]);
    }
#pragma unroll
    for (int mi = 0; mi < 2; ++mi)
#pragma unroll
      for (int ni = 0; ni < 8; ++ni)
        acc[mi][ni] = __builtin_amdgcn_mfma_f32_16x16x32_bf16(af[mi], bfr[ni], acc[mi][ni], 0, 0, 0);
    __syncthreads();
    cur ^= 1;
  }

#pragma unroll
  for (int mi = 0; mi < 2; ++mi)
#pragma unroll
    for (int ni = 0; ni < 8; ++ni) {
      const float* rs = (ni < 4) ? de.rs0 : de.rs1;
#pragma unroll
      for (int r = 0; r < 4; ++r) {
        int row = brow + wave * 32 + mi * 16 + fq * 4 + r;
        int col = ni * 16 + fr;
        de.out[(size_t)row * 128 + col] = f2bf(acc[mi][ni][r] * rs[row]);
      }
    }
}

// ===== batched CSR gather (width 64, z row stride 128) =====================
struct GDesc { const ushort_t* z0; const uint_t* rp0; const uint_t* cs0; const float* s0;
               const ushort_t* z1; const uint_t* rp1; const uint_t* cs1; const float* s1;
               const float* b0; const float* b1; ushort_t* out; int nd; };
struct GDescs { GDesc d[3]; };

__global__ __launch_bounds__(256) void gather_batched_kernel(GDescs ds) {
  GDesc de = ds.d[blockIdx.z];
  int d = blockIdx.x * 4 + (threadIdx.x >> 6);
  if (d >= de.nd) return;
  int c = threadIdx.x & 63;
  float acc;
  {
    uint_t e = de.rp0[d], ee = de.rp0[d + 1];
    float a0 = 0, a1 = 0, a2 = 0, a3 = 0;
    for (; e + 4 <= ee; e += 4) {
      uint_t s0 = de.cs0[e], s1 = de.cs0[e + 1], s2 = de.cs0[e + 2], s3 = de.cs0[e + 3];
      a0 += bf2f(de.z0[s0 * kZS + c]); a1 += bf2f(de.z0[s1 * kZS + c]);
      a2 += bf2f(de.z0[s2 * kZS + c]); a3 += bf2f(de.z0[s3 * kZS + c]);
    }
    for (; e < ee; ++e) a0 += bf2f(de.z0[de.cs0[e] * kZS + c]);
    acc = (a0 + a1 + a2 + a3) * de.s0[d];
  }
  {
    uint_t e = de.rp1[d], ee = de.rp1[d + 1];
    float a0 = 0, a1 = 0, a2 = 0, a3 = 0;
    for (; e + 4 <= ee; e += 4) {
      uint_t s0 = de.cs1[e], s1 = de.cs1[e + 1], s2 = de.cs1[e + 2], s3 = de.cs1[e + 3];
      a0 += bf2f(de.z1[s0 * kZS + c]); a1 += bf2f(de.z1[s1 * kZS + c]);
      a2 += bf2f(de.z1[s2 * kZS + c]); a3 += bf2f(de.z1[s3 * kZS + c]);
    }
    for (; e < ee; ++e) a0 += bf2f(de.z1[de.cs1[e] * kZS + c]);
    acc += (a0 + a1 + a2 + a3) * de.s1[d];
  }
  acc += de.b0[c] + de.b1[c];
  de.out[(size_t)d * 64 + c] = f2bf(acc);
}

// ===== layer-3 gather (width 128, d<2048) fused with L1 normalize ==========
__global__ __launch_bounds__(256) void gather128_l1_kernel(
    const ushort_t* __restrict__ zD, const uint_t* __restrict__ rpD, const uint_t* __restrict__ csD,
    const float* __restrict__ sInD,
    const ushort_t* __restrict__ zM, const uint_t* __restrict__ rpM, const uint_t* __restrict__ csM,
    const float* __restrict__ sInM,
    const float* __restrict__ bD, const float* __restrict__ bM,
    float* __restrict__ emb, ushort_t* __restrict__ embb) {
  int d = blockIdx.x * 4 + (threadIdx.x >> 6);
  int c = threadIdx.x & 63;
  float v0 = 0, v1 = 0;
  {
    uint_t e = rpD[d], ee = rpD[d + 1];
    float a0 = 0, a1 = 0, h0 = 0, h1 = 0;
    for (; e + 2 <= ee; e += 2) {
      uint_t s0 = csD[e], s1 = csD[e + 1];
      a0 += bf2f(zD[s0 * 128 + c]);      h0 += bf2f(zD[s0 * 128 + 64 + c]);
      a1 += bf2f(zD[s1 * 128 + c]);      h1 += bf2f(zD[s1 * 128 + 64 + c]);
    }
    if (e < ee) { uint_t s = csD[e]; a0 += bf2f(zD[s * 128 + c]); h0 += bf2f(zD[s * 128 + 64 + c]); }
    v0 += (a0 + a1) * sInD[d]; v1 += (h0 + h1) * sInD[d];
  }
  {
    uint_t e = rpM[d], ee = rpM[d + 1];
    float a0 = 0, a1 = 0, h0 = 0, h1 = 0;
    for (; e + 2 <= ee; e += 2) {
      uint_t s0 = csM[e], s1 = csM[e + 1];
      a0 += bf2f(zM[s0 * 128 + c]);      h0 += bf2f(zM[s0 * 128 + 64 + c]);
      a1 += bf2f(zM[s1 * 128 + c]);      h1 += bf2f(zM[s1 * 128 + 64 + c]);
    }
    if (e < ee) { uint_t s = csM[e]; a0 += bf2f(zM[s * 128 + c]); h0 += bf2f(zM[s * 128 + 64 + c]); }
    v0 += (a0 + a1) * sInM[d]; v1 += (h0 + h1) * sInM[d];
  }
  v0 += bD[c] + bM[c];
  v1 += bD[64 + c] + bM[64 + c];
  float a = fabsf(v0) + fabsf(v1);
#pragma unroll
  for (int o = 32; o > 0; o >>= 1) a += __shfl_xor(a, o);
  float l1 = fmaxf(a, 1e-12f);
  float e0 = v0 / l1, e1 = v1 / l1;
  emb[d * kOUTF + c] = e0;
  emb[d * kOUTF + 64 + c] = e1;
  embb[d * kOUTF + c] = f2bf(e0);
  embb[d * kOUTF + 64 + c] = f2bf(e1);
}

// ===== split-K reduce ======================================================
__global__ void reducek_kernel(const float* __restrict__ P, float* __restrict__ out,
                               int n4, int S) {
  int idx = blockIdx.x * 256 + threadIdx.x;
  if (idx >= n4) return;
  float4 a = ((const float4*)P)[idx];
  for (int s = 1; s < S; ++s) {
    float4 b = ((const float4*)P)[(size_t)s * n4 + idx];
    a.x += b.x; a.y += b.y; a.z += b.z; a.w += b.w;
  }
  ((float4*)out)[idx] = a;
}

extern "C" void kernel_launch(void* const* d_in, const int* in_sizes, int n_in,
                              void* d_out, int out_size, void* d_ws, size_t ws_size,
                              hipStream_t stream) {
  const float* h_L = (const float*)d_in[0];
  const float* h_D = (const float*)d_in[1];
  const float* h_M = (const float*)d_in[2];
  const float* Adj = (const float*)d_in[3];
  EdgePtrs ep;
  for (int i = 0; i < 12; ++i) ep.p[i] = (const int*)d_in[4 + i];
  const float* W[3]  = {(const float*)d_in[16], (const float*)d_in[18], (const float*)d_in[20]};
  const float* Bb[3] = {(const float*)d_in[17], (const float*)d_in[19], (const float*)d_in[21]};
  const float* f1_w = (const float*)d_in[22];
  const float* f1_b = (const float*)d_in[23];
  const float* f2_w = (const float*)d_in[24];
  const float* f2_b = (const float*)d_in[25];
  const float* f3_w = (const float*)d_in[26];
  const float* f3_b = (const float*)d_in[27];
  const float* f4_w = (const float*)d_in[28];
  const float* f4_b = (const float*)d_in[29];

  // ---- workspace layout ----
  float* ws = (float*)d_ws;
  size_t off = 0;
  auto allocF = [&](size_t n) { float* p = ws + off; off += (n + 3) & ~(size_t)3; return p; };
  auto allocU = [&](size_t n) { return (uint_t*)allocF(n); };
  auto allocB = [&](size_t n) { return (ushort_t*)allocF((n + 1) / 2); };

  uint_t* part   = allocU((size_t)12 * kHB * 16384);   // 12.6 MB, reused as z bufs
  uint_t* cnts   = allocU((size_t)12 * 16384);
  float*  degscale = allocF((size_t)12 * 16384);
  uint_t* rp_all = allocU(45062 + 2);
  uint_t* ofs    = allocU((size_t)6 * kHB * 16384);
  uint_t* csr    = allocU((size_t)6 * kE);
  float* x1f   = allocF((size_t)kSIZE * 256);
  ushort_t* hLb  = allocB((size_t)kNL * kFEAT);
  ushort_t* hDb  = allocB((size_t)kND * kFEAT);
  ushort_t* hMb  = allocB((size_t)kNM * kFEAT);
  ushort_t* Adjb = allocB((size_t)kSIZE * kITEMS);
  ushort_t* aLb  = allocB((size_t)kNL * kHID);
  ushort_t* aDb  = allocB((size_t)kND * kHID);
  ushort_t* aMb  = allocB((size_t)kNM * kHID);
  ushort_t* WLt  = allocB((size_t)128 * kFEAT);   // layer1 [W0;W2]^T
  ushort_t* WDt  = allocB((size_t)128 * kFEAT);   // [W1;W4]^T
  ushort_t* WMt  = allocB((size_t)128 * kFEAT);   // [W3;W5]^T
  ushort_t* WL2t = allocB((size_t)128 * kHID);
  ushort_t* WD2t = allocB((size_t)128 * kHID);
  ushort_t* WM2t = allocB((size_t)128 * kHID);
  ushort_t* W3t1 = allocB((size_t)kOUTF * kHID);
  ushort_t* W3t3 = allocB((size_t)kOUTF * kHID);
  ushort_t* f1t  = allocB((size_t)256 * (kITEMS + kOUTF));
  ushort_t* f2t  = allocB((size_t)512 * 256);
  ushort_t* f3t  = allocB((size_t)1024 * 512);
  ushort_t* f4t  = allocB((size_t)kITEMS * 1024);
  ushort_t* embb = allocB((size_t)kSIZE * kOUTF);
  ushort_t* x1b  = allocB((size_t)kSIZE * 256);
  ushort_t* x2b  = allocB((size_t)kSIZE * 512);
  ushort_t* x3b  = allocB((size_t)kSIZE * 1024);

  // split-K partials if workspace allows
  int S = 1;
  float* partK = x1f;
  if ((off + (size_t)8 * kSIZE * 256 + 16) * 4 <= ws_size) {
    S = 8;
    partK = allocF((size_t)8 * kSIZE * 256);
  }

  // z buffers alias `part` (dead after chunkofs/fill)
  ushort_t* zL  = (ushort_t*)part;                       // 16384 x 128
  ushort_t* zD  = zL + (size_t)kNL * kZS;                // 4096 x 128
  ushort_t* zM  = zD + (size_t)kND * kZS;                // 2048 x 128
  ushort_t* zD3 = zM + (size_t)kNM * kZS;                // 4096 x 128
  ushort_t* zM3 = zD3 + (size_t)kND * kZS;               // 2048 x 128

  I6 ndI; const int ndst_[6] = {kND, kNL, kNM, kNL, kNM, kND};
  for (int t = 0; t < 6; ++t) ndI.v[t] = ndst_[t];
  I6 rpo; { int r = 0; for (int t = 0; t < 6; ++t) { rpo.v[t] = r; r += ndst_[t] + 1; } }
  auto dsc = [&](int k) { return degscale + ((size_t)k << 14); };

  // ---- 1) one prep launch: converts + all weight transposes ----
  PJobs pj; int nj = 0; int totblk = 0;
  auto addCvt = [&](const float* in, ushort_t* out, size_t n) {
    int n4 = (int)(n / 4);
    pj.j[nj] = {in, out, n4, 0, 0, (n4 + 255) / 256}; totblk += pj.j[nj].nblk; ++nj;
  };
  auto addT = [&](const float* in, ushort_t* out, int K, int N) {
    pj.j[nj] = {in, out, K, N, 1, (N / 32) * (K / 32)}; totblk += pj.j[nj].nblk; ++nj;
  };
  addCvt(h_L, hLb, (size_t)kNL * kFEAT);
  addCvt(h_D, hDb, (size_t)kND * kFEAT);
  addCvt(h_M, hMb, (size_t)kNM * kFEAT);
  addCvt(Adj, Adjb, (size_t)kSIZE * kITEMS);
  // layer1 merged weights (K=256, each slice 64 rows)
  addT(W[0] + (size_t)0 * kFEAT * kHID, WLt + (size_t)0 * kFEAT, kFEAT, kHID);
  addT(W[0] + (size_t)2 * kFEAT * kHID, WLt + (size_t)64 * kFEAT, kFEAT, kHID);
  addT(W[0] + (size_t)1 * kFEAT * kHID, WDt + (size_t)0 * kFEAT, kFEAT, kHID);
  addT(W[0] + (size_t)4 * kFEAT * kHID, WDt + (size_t)64 * kFEAT, kFEAT, kHID);
  addT(W[0] + (size_t)3 * kFEAT * kHID, WMt + (size_t)0 * kFEAT, kFEAT, kHID);
  addT(W[0] + (size_t)5 * kFEAT * kHID, WMt + (size_t)64 * kFEAT, kFEAT, kHID);
  // layer2 merged weights (K=64)
  addT(W[1] + (size_t)0 * kHID * kHID, WL2t + (size_t)0 * kHID, kHID, kHID);
  addT(W[1] + (size_t)2 * kHID * kHID, WL2t + (size_t)64 * kHID, kHID, kHID);
  addT(W[1] + (size_t)1 * kHID * kHID, WD2t + (size_t)0 * kHID, kHID, kHID);
  addT(W[1] + (size_t)4 * kHID * kHID, WD2t + (size_t)64 * kHID, kHID, kHID);
  addT(W[1] + (size_t)3 * kHID * kHID, WM2t + (size_t)0 * kHID, kHID, kHID);
  addT(W[1] + (size_t)5 * kHID * kHID, WM2t + (size_t)64 * kHID, kHID, kHID);
  // layer3: only types 1, 3 (N=128)
  addT(W[2] + (size_t)1 * kHID * kOUTF, W3t1, kHID, kOUTF);
  addT(W[2] + (size_t)3 * kHID * kOUTF, W3t3, kHID, kOUTF);
  // MLP weights
  addT(f1_w, f1t, kITEMS + kOUTF, 256);
  addT(f2_w, f2t, 256, 512);
  addT(f3_w, f3t, 512, 1024);
  addT(f4_w, f4t, 1024, kITEMS);
  pj.n = nj;
  prep_kernel<<<totblk, 256, 0, stream>>>(pj);

  // ---- 2) degree + CSR build ----
  hist_kernel<<<12 * kHB, 256, 0, stream>>>(ep, part);
  reduce_finalize_kernel<<<12 * 16384 / 256, 256, 0, stream>>>(part, cnts, degscale);
  scan_kernel<<<6, 1024, 0, stream>>>(cnts, rp_all, rpo, ndI);
  chunkofs_kernel<<<6 * 16384 / 256, 256, 0, stream>>>(part, rp_all, rpo, ndI, ofs);
  fill_kernel<<<6 * kHB, 256, 0, stream>>>(ep, ofs, csr);

  // ---- 3) Adj @ f1_w[:4096] with split-K ----
  gemm_bf16_kernel<<<dim3(2, 16, S), 256, 0, stream>>>(
      Adjb, f1t, nullptr, nullptr, 0, kSIZE, 256, kITEMS, kITEMS + kOUTF,
      nullptr, 0, kITEMS / S, partK);
  if (S > 1)
    reducek_kernel<<<kSIZE * 256 / 4 / 256, 256, 0, stream>>>(partK, x1f, kSIZE * 256 / 4, S);

  // ---- 4) GNN layers 1 & 2 ----
  const ushort_t* curb[3] = {hLb, hDb, hMb};
  for (int layer = 0; layer < 2; ++layer) {
    int K = (layer == 0) ? kFEAT : kHID;
    const ushort_t* WtL = (layer == 0) ? WLt : WL2t;
    const ushort_t* WtD = (layer == 0) ? WDt : WD2t;
    const ushort_t* WtM = (layer == 0) ? WMt : WM2t;
    const float* bl = Bb[layer];
    ZDescs zd;
    zd.d[0] = {curb[0], WtL, zL, dsc(0), dsc(4),  kNL, K};
    zd.d[1] = {curb[1], WtD, zD, dsc(2), dsc(8),  kND, K};
    zd.d[2] = {curb[2], WtM, zM, dsc(6), dsc(10), kNM, K};
    zgemm_batched_kernel<<<dim3(1, kNL / 128, 3), 256, 0, stream>>>(zd);
    GDescs gd;
    // oL <- t1 (zD cols 0-63) + t3 (zM cols 0-63)
    gd.d[0] = {zD, rp_all + rpo.v[1], csr + (size_t)1 * kE, dsc(3),
               zM, rp_all + rpo.v[3], csr + (size_t)3 * kE, dsc(7),
               bl + 1 * kHID, bl + 3 * kHID, aLb, kNL};
    // oD <- t0 (zL cols 0-63) + t5 (zM cols 64-127)
    gd.d[1] = {zL, rp_all + rpo.v[0], csr + (size_t)0 * kE, dsc(1),
               zM + 64, rp_all + rpo.v[5], csr + (size_t)5 * kE, dsc(11),
               bl + 0 * kHID, bl + 5 * kHID, aDb, kND};
    // oM <- t2 (zL cols 64-127) + t4 (zD cols 64-127)
    gd.d[2] = {zL + 64, rp_all + rpo.v[2], csr + (size_t)2 * kE, dsc(5),
               zD + 64, rp_all + rpo.v[4], csr + (size_t)4 * kE, dsc(9),
               bl + 2 * kHID, bl + 4 * kHID, aMb, kNM};
    gather_batched_kernel<<<dim3(kNL / 4, 1, 3), 256, 0, stream>>>(gd);
    curb[0] = aLb; curb[1] = aDb; curb[2] = aMb;
  }

  // ---- 5) layer 3 (types 1: D->L, 3: M->L; rows < 2048) + L1 norm ----
  float* emb  = (float*)d_out;
  float* outx = (float*)d_out + (size_t)kSIZE * kOUTF;
  {
    ZDescs zd;
    zd.d[0] = {curb[1], W3t1, zD3, dsc(2), dsc(2), kND, kHID};
    zd.d[1] = {curb[2], W3t3, zM3, dsc(6), dsc(6), kNM, kHID};
    zd.d[2] = zd.d[1];
    zgemm_batched_kernel<<<dim3(1, kND / 128, 2), 256, 0, stream>>>(zd);
    gather128_l1_kernel<<<kSIZE / 4, 256, 0, stream>>>(
        zD3, rp_all + rpo.v[1], csr + (size_t)1 * kE, dsc(3),
        zM3, rp_all + rpo.v[3], csr + (size_t)3 * kE, dsc(7),
        Bb[2] + 1 * kOUTF, Bb[2] + 3 * kOUTF, emb, embb);
  }

  // ---- 6) MLP ----
  gemm_bf16_kernel<<<dim3(2, 16, 1), 256, 0, stream>>>(
      embb, f1t + kITEMS, x1f, x1b, 1, kSIZE, 256, kOUTF, kITEMS + kOUTF,
      f1_b, 1, 0, nullptr);
  gemm_bf16_kernel<<<dim3(4, 16, 1), 256, 0, stream>>>(
      x1b, f2t, nullptr, x2b, 1, kSIZE, 512, 256, 256, f2_b, 1, 0, nullptr);
  gemm_bf16_kernel<<<dim3(8, 16, 1), 256, 0, stream>>>(
      x2b, f3t, nullptr, x3b, 1, kSIZE, 1024, 512, 512, f3_b, 1, 0, nullptr);
  gemm_bf16_kernel<<<dim3(32, 16, 1), 256, 0, stream>>>(
      x3b, f4t, nullptr, outx, 0, kSIZE, kITEMS, 1024, 1024, f4_b, 2, 0, nullptr);
}

// Round 7
// 427.285 us; speedup vs baseline: 1.0075x; 1.0006x over previous
//
#include <hip/hip_runtime.h>

constexpr int kNL = 16384, kND = 4096, kNM = 2048;
constexpr int kE = 262144;              // 2^18
constexpr int kFEAT = 256, kHID = 64, kOUTF = 128;
constexpr int kITEMS = 4096, kSIZE = 2048;
constexpr int kHB = 16;                 // histogram chunks per index array
constexpr int kZS = 128;                // z row stride (merged 2-type layout)

typedef unsigned short ushort_t;
typedef unsigned int uint_t;
typedef __attribute__((ext_vector_type(8))) short short8v;
typedef __attribute__((ext_vector_type(4))) float f32x4;

struct EdgePtrs { const int* p[12]; };
struct I6 { int v[6]; };

__device__ inline ushort_t f2bf(float f) {
  unsigned u = __builtin_bit_cast(unsigned, f);
  unsigned r = u + 0x7fffu + ((u >> 16) & 1u);
  return (ushort_t)(r >> 16);
}
__device__ inline float bf2f(ushort_t b) {
  unsigned u = ((unsigned)b) << 16;
  return __builtin_bit_cast(float, u);
}

// async global->LDS, 16 B per lane (global_load_lds_dwordx4)
__device__ __forceinline__ void gload16(const ushort_t* g, ushort_t* l) {
  __builtin_amdgcn_global_load_lds(
      (const __attribute__((address_space(1))) void*)g,
      (__attribute__((address_space(3))) void*)l, 16, 0, 0);
}

// bijective XCD swizzle (m204), y-fastest orientation for L2 panel locality
__device__ __forceinline__ void xcd_swizzle(int& bx, int& by) {
  int gx = gridDim.x, gy = gridDim.y;
  int nwg = gx * gy;
  int orig = by * gx + bx;
  int q = nwg >> 3, r = nwg & 7;
  int xcd = orig & 7, loc = orig >> 3;
  int s = ((xcd < r) ? xcd * (q + 1) : r * (q + 1) + (xcd - r) * q) + loc;
  by = s % gy;
  bx = s / gy;
}

// ===== prep: all fp32->bf16 converts + transpose-converts in ONE launch ====
struct PJob { const float* in; ushort_t* out; int A; int B; int kind; int nblk; };
struct PJobs { PJob j[24]; int n; };

__global__ __launch_bounds__(256) void prep_kernel(PJobs jobs) {
  __shared__ float t[32][33];
  int b = blockIdx.x;
  int ji = 0;
  while (ji < jobs.n && b >= jobs.j[ji].nblk) { b -= jobs.j[ji].nblk; ++ji; }
  if (ji >= jobs.n) return;
  PJob jb = jobs.j[ji];
  if (jb.kind == 0) {                       // flat convert, A = n4
    int idx = b * 256 + threadIdx.x;
    if (idx >= jb.A) return;
    float4 v = ((const float4*)jb.in)[idx];
    ushort_t* o = jb.out + (size_t)idx * 4;
    o[0] = f2bf(v.x); o[1] = f2bf(v.y); o[2] = f2bf(v.z); o[3] = f2bf(v.w);
  } else {                                  // transpose: in [K][N] -> out [N][K]; A=K, B=N
    int K = jb.A, N = jb.B;
    int tpr = N >> 5;
    int n0 = (b % tpr) * 32, k0 = (b / tpr) * 32;
    int tx = threadIdx.x & 31, ty = threadIdx.x >> 5;
#pragma unroll
    for (int i = 0; i < 32; i += 8)
      t[ty + i][tx] = jb.in[(size_t)(k0 + ty + i) * N + n0 + tx];
    __syncthreads();
#pragma unroll
    for (int i = 0; i < 32; i += 8)
      jb.out[(size_t)(n0 + ty + i) * K + k0 + tx] = f2bf(t[tx][ty + i]);
  }
}

// ===== degree/CSR build (no global atomics) ================================
__global__ __launch_bounds__(256) void hist_kernel(EdgePtrs ep, uint_t* __restrict__ part) {
  __shared__ uint_t bins[16384];
  int k = blockIdx.x >> 4, chunk = blockIdx.x & (kHB - 1);
  for (int i = threadIdx.x; i < 16384; i += 256) bins[i] = 0;
  __syncthreads();
  const int* arr = ep.p[k];
  int base = chunk * (kE / kHB);
  for (int i = threadIdx.x; i < kE / kHB; i += 256)
    atomicAdd(&bins[arr[base + i]], 1u);
  __syncthreads();
  uint_t* o = part + ((size_t)blockIdx.x << 14);
  for (int i = threadIdx.x; i < 16384; i += 256) o[i] = bins[i];
}

__global__ void reduce_finalize_kernel(const uint_t* __restrict__ part,
                                       uint_t* __restrict__ cnts,
                                       float* __restrict__ degscale) {
  int idx = blockIdx.x * 256 + threadIdx.x;   // grid = 12*16384/256
  int k = idx >> 14, bin = idx & 16383;
  uint_t s = 0;
  for (int c = 0; c < kHB; ++c) s += part[((size_t)(k * kHB + c) << 14) + bin];
  cnts[idx] = s;
  degscale[idx] = rsqrtf((float)max(s, 1u));
}

__global__ __launch_bounds__(1024) void scan_kernel(const uint_t* __restrict__ cnts,
                                                    uint_t* __restrict__ rp_all,
                                                    I6 rpoff, I6 nd) {
  __shared__ uint_t sums[1024];
  int t = blockIdx.x;
  int n = nd.v[t];
  const uint_t* c = cnts + ((size_t)(2 * t + 1) << 14);
  uint_t* rp = rp_all + rpoff.v[t];
  int tid = threadIdx.x;
  int seg = n >> 10;
  uint_t s = 0;
  for (int j = 0; j < seg; ++j) s += c[tid * seg + j];
  sums[tid] = s;
  __syncthreads();
  for (int o = 1; o < 1024; o <<= 1) {
    uint_t v = (tid >= o) ? sums[tid - o] : 0u;
    __syncthreads();
    sums[tid] += v;
    __syncthreads();
  }
  uint_t run = sums[tid] - s;   // exclusive
  for (int j = 0; j < seg; ++j) { rp[tid * seg + j] = run; run += c[tid * seg + j]; }
  if (tid == 1023) rp[n] = run;
}

__global__ void chunkofs_kernel(const uint_t* __restrict__ part,
                                const uint_t* __restrict__ rp_all,
                                I6 rpoff, I6 nd, uint_t* __restrict__ ofs) {
  int idx = blockIdx.x * 256 + threadIdx.x;   // grid = 6*16384/256
  int t = idx >> 14, bin = idx & 16383;
  if (bin >= nd.v[t]) return;
  uint_t run = (rp_all + rpoff.v[t])[bin];
  for (int c = 0; c < kHB; ++c) {
    ofs[((size_t)(t * kHB + c) << 14) + bin] = run;
    run += part[((size_t)((2 * t + 1) * kHB + c) << 14) + bin];
  }
}

__global__ __launch_bounds__(256) void fill_kernel(EdgePtrs ep,
                                                   const uint_t* __restrict__ ofs,
                                                   uint_t* __restrict__ csr_all) {
  __shared__ uint_t cursor[16384];
  int t = blockIdx.x >> 4, chunk = blockIdx.x & (kHB - 1);
  const uint_t* o = ofs + ((size_t)(t * kHB + chunk) << 14);
  for (int i = threadIdx.x; i < 16384; i += 256) cursor[i] = o[i];
  __syncthreads();
  const int* srcp = ep.p[2 * t];
  const int* dstp = ep.p[2 * t + 1];
  int base = chunk * (kE / kHB);
  uint_t* csr = csr_all + (size_t)t * kE;
  for (int i = threadIdx.x; i < kE / kHB; i += 256) {
    int e = base + i;
    int d = dstp[e];
    uint_t pos = atomicAdd(&cursor[d], 1u);
    csr[pos] = (uint_t)srcp[e];
  }
}

// ===== generic bf16 MFMA GEMM, 128x128 tile ================================
// Triple-buffered LDS + counted vmcnt (T4): DMA for tile i+2 issued after the
// barrier of tile i; per-iter wait is vmcnt(4) (one stage in flight), never 0.
__global__ __launch_bounds__(256) void gemm_bf16_kernel(
    const ushort_t* __restrict__ A, const ushort_t* __restrict__ Bt,
    const float* __restrict__ Cin, void* __restrict__ out, int outBf16,
    int M, int N, int K, int ldb,
    const float* __restrict__ bias, int act,
    int kChunk, float* __restrict__ partOut) {
  __shared__ ushort_t As[3][4096];   // 3 x 8 KB
  __shared__ ushort_t Bs[3][4096];
  int tid = threadIdx.x;
  int wave = tid >> 6, lane = tid & 63;
  int bx = blockIdx.x, by = blockIdx.y;
  xcd_swizzle(bx, by);
  int brow = by * 128, bcol = bx * 128;
  int kStart = partOut ? blockIdx.z * kChunk : 0;
  int kLen = partOut ? kChunk : K;
  int nsteps = kLen >> 5;

  // staging map: LDS linear; global slot pre-swizzled within 64B row
  int arow = tid >> 2;                 // 0..63 (and +64 for second half)
  int aslot = tid & 3;                 // 16B slot within 64B row
  int sw = (arow >> 1) & 3;            // same for row and row+64
  const ushort_t* gA = A + (size_t)(brow + arow) * K + kStart + (aslot ^ sw) * 8;
  const ushort_t* gB = Bt + (size_t)(bcol + arow) * ldb + kStart + (aslot ^ sw) * 8;
  size_t sA64 = (size_t)64 * K;
  size_t sB64 = (size_t)64 * ldb;

  int fr = lane & 15, fq = lane >> 4;
  f32x4 acc[2][8] = {};

#define STAGE_G(buf, koff)                                   \
  do {                                                       \
    gload16(gA + (koff), &As[buf][tid * 8]);                 \
    gload16(gA + sA64 + (koff), &As[buf][2048 + tid * 8]);   \
    gload16(gB + (koff), &Bs[buf][tid * 8]);                 \
    gload16(gB + sB64 + (koff), &Bs[buf][2048 + tid * 8]);   \
  } while (0)

  STAGE_G(0, 0);
  if (nsteps > 1) STAGE_G(1, 32);

  int cb = 0, sb = 2;
  for (int i = 0; i < nsteps; ++i) {
    if (i + 1 < nsteps) asm volatile("s_waitcnt vmcnt(4)\ns_barrier" ::: "memory");
    else                asm volatile("s_waitcnt vmcnt(0)\ns_barrier" ::: "memory");
    if (i + 2 < nsteps) { STAGE_G(sb, (i + 2) * 32); }
    short8v af[2], bfr[8];
#pragma unroll
    for (int mi = 0; mi < 2; ++mi) {
      int row = wave * 32 + mi * 16 + fr;
      af[mi] = *(const short8v*)(&As[cb][row * 32 + ((fq ^ ((row >> 1) & 3)) * 8)]);
    }
#pragma unroll
    for (int ni = 0; ni < 8; ++ni) {
      int row = ni * 16 + fr;
      bfr[ni] = *(const short8v*)(&Bs[cb][row * 32 + ((fq ^ ((row >> 1) & 3)) * 8)]);
    }
#pragma unroll
    for (int mi = 0; mi < 2; ++mi)
#pragma unroll
      for (int ni = 0; ni < 8; ++ni)
        acc[mi][ni] = __builtin_amdgcn_mfma_f32_16x16x32_bf16(af[mi], bfr[ni], acc[mi][ni], 0, 0, 0);
    cb = (cb == 2) ? 0 : cb + 1;
    sb = (sb == 2) ? 0 : sb + 1;
  }
#undef STAGE_G

  if (partOut) {
    float* o = partOut + (size_t)blockIdx.z * M * N;
#pragma unroll
    for (int mi = 0; mi < 2; ++mi)
#pragma unroll
      for (int ni = 0; ni < 8; ++ni)
#pragma unroll
        for (int r = 0; r < 4; ++r) {
          int row = brow + wave * 32 + mi * 16 + fq * 4 + r;
          int col = bcol + ni * 16 + fr;
          o[(size_t)row * N + col] = acc[mi][ni][r];
        }
    return;
  }
#pragma unroll
  for (int mi = 0; mi < 2; ++mi)
#pragma unroll
    for (int ni = 0; ni < 8; ++ni)
#pragma unroll
      for (int r = 0; r < 4; ++r) {
        int row = brow + wave * 32 + mi * 16 + fq * 4 + r;
        int col = bcol + ni * 16 + fr;
        float v = acc[mi][ni][r];
        if (Cin) v += Cin[(size_t)row * N + col];
        if (bias) v += bias[col];
        if (act == 1) v = fmaxf(v, 0.0f);
        else if (act == 2) v = 1.0f / (1.0f + expf(-v));
        if (outBf16) ((ushort_t*)out)[(size_t)row * N + col] = f2bf(v);
        else ((float*)out)[(size_t)row * N + col] = v;
      }
}

// ===== batched z GEMM: N=128, out = [rs0|rs1] .* (A @ Bt^T), bf16 ==========
struct ZDesc { const ushort_t* A; const ushort_t* Bt; ushort_t* out;
               const float* rs0; const float* rs1; int M; int K; };
struct ZDescs { ZDesc d[3]; };

__global__ __launch_bounds__(256) void zgemm_batched_kernel(ZDescs ds) {
  __shared__ ushort_t As[3][4096];
  __shared__ ushort_t Bs[3][4096];
  ZDesc de = ds.d[blockIdx.z];
  // swizzle y within the slice (spreads active blocks across XCDs)
  int gy = gridDim.y;
  int yq = gy >> 3;
  int ys = (blockIdx.y & 7) * yq + (blockIdx.y >> 3);
  int brow = ys * 128;
  if (brow >= de.M) return;
  int K = de.K;
  int nsteps = K >> 5;
  int tid = threadIdx.x;
  int wave = tid >> 6, lane = tid & 63;

  int arow = tid >> 2, aslot = tid & 3;
  int sw = (arow >> 1) & 3;
  const ushort_t* gA = de.A + (size_t)(brow + arow) * K + (aslot ^ sw) * 8;
  const ushort_t* gB = de.Bt + (size_t)arow * K + (aslot ^ sw) * 8;
  size_t s64 = (size_t)64 * K;

  int fr = lane & 15, fq = lane >> 4;
  f32x4 acc[2][8] = {};

#define STAGE_Z(buf, koff)                                  \
  do {                                                      \
    gload16(gA + (koff), &As[buf][tid * 8]);                \
    gload16(gA + s64 + (koff), &As[buf][2048 + tid * 8]);   \
    gload16(gB + (koff), &Bs[buf][tid * 8]);                \
    gload16(gB + s64 + (koff), &Bs[buf][2048 + tid * 8]);   \
  } while (0)

  STAGE_Z(0, 0);
  if (nsteps > 1) STAGE_Z(1, 32);

  int cb = 0, sb = 2;
  for (int i = 0; i < nsteps; ++i) {
    if (i + 1 < nsteps) asm volatile("s_waitcnt vmcnt(4)\ns_barrier" ::: "memory");
    else                asm volatile("s_waitcnt vmcnt(0)\ns_barrier" ::: "memory");
    if (i + 2 < nsteps) { STAGE_Z(sb, (i + 2) * 32); }
    short8v af[2], bfr[8];
#pragma unroll
    for (int mi = 0; mi < 2; ++mi) {
      int row = wave * 32 + mi * 16 + fr;
      af[mi] = *(const short8v*)(&As[cb][row * 32 + ((fq ^ ((row >> 1) & 3)) * 8)]);
    }
#pragma unroll
    for (int ni = 0; ni < 8; ++ni) {
      int row = ni * 16 + fr;
      bfr[ni] = *(const short8v*)(&Bs[cb][row * 32 + ((fq ^ ((row >> 1) & 3)) * 8)]);
    }
#pragma unroll
    for (int mi = 0; mi < 2; ++mi)
#pragma unroll
      for (int ni = 0; ni < 8; ++ni)
        acc[mi][ni] = __builtin_amdgcn_mfma_f32_16x16x32_bf16(af[mi], bfr[ni], acc[mi][ni], 0, 0, 0);
    cb = (cb == 2) ? 0 : cb + 1;
    sb = (sb == 2) ? 0 : sb + 1;
  }
#undef STAGE_Z

#pragma unroll
  for (int mi = 0; mi < 2; ++mi)
#pragma unroll
    for (int ni = 0; ni < 8; ++ni) {
      const float* rs = (ni < 4) ? de.rs0 : de.rs1;
#pragma unroll
      for (int r = 0; r < 4; ++r) {
        int row = brow + wave * 32 + mi * 16 + fq * 4 + r;
        int col = ni * 16 + fr;
        de.out[(size_t)row * 128 + col] = f2bf(acc[mi][ni][r] * rs[row]);
      }
    }
}

// ===== batched CSR gather (width 64, z row stride 128) =====================
struct GDesc { const ushort_t* z0; const uint_t* rp0; const uint_t* cs0; const float* s0;
               const ushort_t* z1; const uint_t* rp1; const uint_t* cs1; const float* s1;
               const float* b0; const float* b1; ushort_t* out; int nd; };
struct GDescs { GDesc d[3]; };

__global__ __launch_bounds__(256) void gather_batched_kernel(GDescs ds) {
  GDesc de = ds.d[blockIdx.z];
  int d = blockIdx.x * 4 + (threadIdx.x >> 6);
  if (d >= de.nd) return;
  int c = threadIdx.x & 63;
  float acc;
  {
    uint_t e = de.rp0[d], ee = de.rp0[d + 1];
    float a0 = 0, a1 = 0, a2 = 0, a3 = 0;
    for (; e + 4 <= ee; e += 4) {
      uint_t s0 = de.cs0[e], s1 = de.cs0[e + 1], s2 = de.cs0[e + 2], s3 = de.cs0[e + 3];
      a0 += bf2f(de.z0[s0 * kZS + c]); a1 += bf2f(de.z0[s1 * kZS + c]);
      a2 += bf2f(de.z0[s2 * kZS + c]); a3 += bf2f(de.z0[s3 * kZS + c]);
    }
    for (; e < ee; ++e) a0 += bf2f(de.z0[de.cs0[e] * kZS + c]);
    acc = (a0 + a1 + a2 + a3) * de.s0[d];
  }
  {
    uint_t e = de.rp1[d], ee = de.rp1[d + 1];
    float a0 = 0, a1 = 0, a2 = 0, a3 = 0;
    for (; e + 4 <= ee; e += 4) {
      uint_t s0 = de.cs1[e], s1 = de.cs1[e + 1], s2 = de.cs1[e + 2], s3 = de.cs1[e + 3];
      a0 += bf2f(de.z1[s0 * kZS + c]); a1 += bf2f(de.z1[s1 * kZS + c]);
      a2 += bf2f(de.z1[s2 * kZS + c]); a3 += bf2f(de.z1[s3 * kZS + c]);
    }
    for (; e < ee; ++e) a0 += bf2f(de.z1[de.cs1[e] * kZS + c]);
    acc += (a0 + a1 + a2 + a3) * de.s1[d];
  }
  acc += de.b0[c] + de.b1[c];
  de.out[(size_t)d * 64 + c] = f2bf(acc);
}

// ===== layer-3 gather (width 128, d<2048) fused with L1 normalize ==========
__global__ __launch_bounds__(256) void gather128_l1_kernel(
    const ushort_t* __restrict__ zD, const uint_t* __restrict__ rpD, const uint_t* __restrict__ csD,
    const float* __restrict__ sInD,
    const ushort_t* __restrict__ zM, const uint_t* __restrict__ rpM, const uint_t* __restrict__ csM,
    const float* __restrict__ sInM,
    const float* __restrict__ bD, const float* __restrict__ bM,
    float* __restrict__ emb, ushort_t* __restrict__ embb) {
  int d = blockIdx.x * 4 + (threadIdx.x >> 6);
  int c = threadIdx.x & 63;
  float v0 = 0, v1 = 0;
  {
    uint_t e = rpD[d], ee = rpD[d + 1];
    float a0 = 0, a1 = 0, h0 = 0, h1 = 0;
    for (; e + 2 <= ee; e += 2) {
      uint_t s0 = csD[e], s1 = csD[e + 1];
      a0 += bf2f(zD[s0 * 128 + c]);      h0 += bf2f(zD[s0 * 128 + 64 + c]);
      a1 += bf2f(zD[s1 * 128 + c]);      h1 += bf2f(zD[s1 * 128 + 64 + c]);
    }
    if (e < ee) { uint_t s = csD[e]; a0 += bf2f(zD[s * 128 + c]); h0 += bf2f(zD[s * 128 + 64 + c]); }
    v0 += (a0 + a1) * sInD[d]; v1 += (h0 + h1) * sInD[d];
  }
  {
    uint_t e = rpM[d], ee = rpM[d + 1];
    float a0 = 0, a1 = 0, h0 = 0, h1 = 0;
    for (; e + 2 <= ee; e += 2) {
      uint_t s0 = csM[e], s1 = csM[e + 1];
      a0 += bf2f(zM[s0 * 128 + c]);      h0 += bf2f(zM[s0 * 128 + 64 + c]);
      a1 += bf2f(zM[s1 * 128 + c]);      h1 += bf2f(zM[s1 * 128 + 64 + c]);
    }
    if (e < ee) { uint_t s = csM[e]; a0 += bf2f(zM[s * 128 + c]); h0 += bf2f(zM[s * 128 + 64 + c]); }
    v0 += (a0 + a1) * sInM[d]; v1 += (h0 + h1) * sInM[d];
  }
  v0 += bD[c] + bM[c];
  v1 += bD[64 + c] + bM[64 + c];
  float a = fabsf(v0) + fabsf(v1);
#pragma unroll
  for (int o = 32; o > 0; o >>= 1) a += __shfl_xor(a, o);
  float l1 = fmaxf(a, 1e-12f);
  float e0 = v0 / l1, e1 = v1 / l1;
  emb[d * kOUTF + c] = e0;
  emb[d * kOUTF + 64 + c] = e1;
  embb[d * kOUTF + c] = f2bf(e0);
  embb[d * kOUTF + 64 + c] = f2bf(e1);
}

// ===== split-K reduce ======================================================
__global__ void reducek_kernel(const float* __restrict__ P, float* __restrict__ out,
                               int n4, int S) {
  int idx = blockIdx.x * 256 + threadIdx.x;
  if (idx >= n4) return;
  float4 a = ((const float4*)P)[idx];
  for (int s = 1; s < S; ++s) {
    float4 b = ((const float4*)P)[(size_t)s * n4 + idx];
    a.x += b.x; a.y += b.y; a.z += b.z; a.w += b.w;
  }
  ((float4*)out)[idx] = a;
}

extern "C" void kernel_launch(void* const* d_in, const int* in_sizes, int n_in,
                              void* d_out, int out_size, void* d_ws, size_t ws_size,
                              hipStream_t stream) {
  const float* h_L = (const float*)d_in[0];
  const float* h_D = (const float*)d_in[1];
  const float* h_M = (const float*)d_in[2];
  const float* Adj = (const float*)d_in[3];
  EdgePtrs ep;
  for (int i = 0; i < 12; ++i) ep.p[i] = (const int*)d_in[4 + i];
  const float* W[3]  = {(const float*)d_in[16], (const float*)d_in[18], (const float*)d_in[20]};
  const float* Bb[3] = {(const float*)d_in[17], (const float*)d_in[19], (const float*)d_in[21]};
  const float* f1_w = (const float*)d_in[22];
  const float* f1_b = (const float*)d_in[23];
  const float* f2_w = (const float*)d_in[24];
  const float* f2_b = (const float*)d_in[25];
  const float* f3_w = (const float*)d_in[26];
  const float* f3_b = (const float*)d_in[27];
  const float* f4_w = (const float*)d_in[28];
  const float* f4_b = (const float*)d_in[29];

  // ---- workspace layout ----
  float* ws = (float*)d_ws;
  size_t off = 0;
  auto allocF = [&](size_t n) { float* p = ws + off; off += (n + 3) & ~(size_t)3; return p; };
  auto allocU = [&](size_t n) { return (uint_t*)allocF(n); };
  auto allocB = [&](size_t n) { return (ushort_t*)allocF((n + 1) / 2); };

  uint_t* part   = allocU((size_t)12 * kHB * 16384);   // 12.6 MB, reused as z bufs
  uint_t* cnts   = allocU((size_t)12 * 16384);
  float*  degscale = allocF((size_t)12 * 16384);
  uint_t* rp_all = allocU(45062 + 2);
  uint_t* ofs    = allocU((size_t)6 * kHB * 16384);
  uint_t* csr    = allocU((size_t)6 * kE);
  float* x1f   = allocF((size_t)kSIZE * 256);
  ushort_t* hLb  = allocB((size_t)kNL * kFEAT);
  ushort_t* hDb  = allocB((size_t)kND * kFEAT);
  ushort_t* hMb  = allocB((size_t)kNM * kFEAT);
  ushort_t* Adjb = allocB((size_t)kSIZE * kITEMS);
  ushort_t* aLb  = allocB((size_t)kNL * kHID);
  ushort_t* aDb  = allocB((size_t)kND * kHID);
  ushort_t* aMb  = allocB((size_t)kNM * kHID);
  ushort_t* WLt  = allocB((size_t)128 * kFEAT);   // layer1 [W0;W2]^T
  ushort_t* WDt  = allocB((size_t)128 * kFEAT);   // [W1;W4]^T
  ushort_t* WMt  = allocB((size_t)128 * kFEAT);   // [W3;W5]^T
  ushort_t* WL2t = allocB((size_t)128 * kHID);
  ushort_t* WD2t = allocB((size_t)128 * kHID);
  ushort_t* WM2t = allocB((size_t)128 * kHID);
  ushort_t* W3t1 = allocB((size_t)kOUTF * kHID);
  ushort_t* W3t3 = allocB((size_t)kOUTF * kHID);
  ushort_t* f1t  = allocB((size_t)256 * (kITEMS + kOUTF));
  ushort_t* f2t  = allocB((size_t)512 * 256);
  ushort_t* f3t  = allocB((size_t)1024 * 512);
  ushort_t* f4t  = allocB((size_t)kITEMS * 1024);
  ushort_t* embb = allocB((size_t)kSIZE * kOUTF);
  ushort_t* x1b  = allocB((size_t)kSIZE * 256);
  ushort_t* x2b  = allocB((size_t)kSIZE * 512);
  ushort_t* x3b  = allocB((size_t)kSIZE * 1024);

  // split-K partials if workspace allows
  int S = 1;
  float* partK = x1f;
  if ((off + (size_t)8 * kSIZE * 256 + 16) * 4 <= ws_size) {
    S = 8;
    partK = allocF((size_t)8 * kSIZE * 256);
  }

  // z buffers alias `part` (dead after chunkofs/fill)
  ushort_t* zL  = (ushort_t*)part;                       // 16384 x 128
  ushort_t* zD  = zL + (size_t)kNL * kZS;                // 4096 x 128
  ushort_t* zM  = zD + (size_t)kND * kZS;                // 2048 x 128
  ushort_t* zD3 = zM + (size_t)kNM * kZS;                // 4096 x 128
  ushort_t* zM3 = zD3 + (size_t)kND * kZS;               // 2048 x 128

  I6 ndI; const int ndst_[6] = {kND, kNL, kNM, kNL, kNM, kND};
  for (int t = 0; t < 6; ++t) ndI.v[t] = ndst_[t];
  I6 rpo; { int r = 0; for (int t = 0; t < 6; ++t) { rpo.v[t] = r; r += ndst_[t] + 1; } }
  auto dsc = [&](int k) { return degscale + ((size_t)k << 14); };

  // ---- 1) one prep launch: converts + all weight transposes ----
  PJobs pj; int nj = 0; int totblk = 0;
  auto addCvt = [&](const float* in, ushort_t* out, size_t n) {
    int n4 = (int)(n / 4);
    pj.j[nj] = {in, out, n4, 0, 0, (n4 + 255) / 256}; totblk += pj.j[nj].nblk; ++nj;
  };
  auto addT = [&](const float* in, ushort_t* out, int K, int N) {
    pj.j[nj] = {in, out, K, N, 1, (N / 32) * (K / 32)}; totblk += pj.j[nj].nblk; ++nj;
  };
  addCvt(h_L, hLb, (size_t)kNL * kFEAT);
  addCvt(h_D, hDb, (size_t)kND * kFEAT);
  addCvt(h_M, hMb, (size_t)kNM * kFEAT);
  addCvt(Adj, Adjb, (size_t)kSIZE * kITEMS);
  // layer1 merged weights (K=256, each slice 64 rows)
  addT(W[0] + (size_t)0 * kFEAT * kHID, WLt + (size_t)0 * kFEAT, kFEAT, kHID);
  addT(W[0] + (size_t)2 * kFEAT * kHID, WLt + (size_t)64 * kFEAT, kFEAT, kHID);
  addT(W[0] + (size_t)1 * kFEAT * kHID, WDt + (size_t)0 * kFEAT, kFEAT, kHID);
  addT(W[0] + (size_t)4 * kFEAT * kHID, WDt + (size_t)64 * kFEAT, kFEAT, kHID);
  addT(W[0] + (size_t)3 * kFEAT * kHID, WMt + (size_t)0 * kFEAT, kFEAT, kHID);
  addT(W[0] + (size_t)5 * kFEAT * kHID, WMt + (size_t)64 * kFEAT, kFEAT, kHID);
  // layer2 merged weights (K=64)
  addT(W[1] + (size_t)0 * kHID * kHID, WL2t + (size_t)0 * kHID, kHID, kHID);
  addT(W[1] + (size_t)2 * kHID * kHID, WL2t + (size_t)64 * kHID, kHID, kHID);
  addT(W[1] + (size_t)1 * kHID * kHID, WD2t + (size_t)0 * kHID, kHID, kHID);
  addT(W[1] + (size_t)4 * kHID * kHID, WD2t + (size_t)64 * kHID, kHID, kHID);
  addT(W[1] + (size_t)3 * kHID * kHID, WM2t + (size_t)0 * kHID, kHID, kHID);
  addT(W[1] + (size_t)5 * kHID * kHID, WM2t + (size_t)64 * kHID, kHID, kHID);
  // layer3: only types 1, 3 (N=128)
  addT(W[2] + (size_t)1 * kHID * kOUTF, W3t1, kHID, kOUTF);
  addT(W[2] + (size_t)3 * kHID * kOUTF, W3t3, kHID, kOUTF);
  // MLP weights
  addT(f1_w, f1t, kITEMS + kOUTF, 256);
  addT(f2_w, f2t, 256, 512);
  addT(f3_w, f3t, 512, 1024);
  addT(f4_w, f4t, 1024, kITEMS);
  pj.n = nj;
  prep_kernel<<<totblk, 256, 0, stream>>>(pj);

  // ---- 2) degree + CSR build ----
  hist_kernel<<<12 * kHB, 256, 0, stream>>>(ep, part);
  reduce_finalize_kernel<<<12 * 16384 / 256, 256, 0, stream>>>(part, cnts, degscale);
  scan_kernel<<<6, 1024, 0, stream>>>(cnts, rp_all, rpo, ndI);
  chunkofs_kernel<<<6 * 16384 / 256, 256, 0, stream>>>(part, rp_all, rpo, ndI, ofs);
  fill_kernel<<<6 * kHB, 256, 0, stream>>>(ep, ofs, csr);

  // ---- 3) Adj @ f1_w[:4096] with split-K ----
  gemm_bf16_kernel<<<dim3(2, 16, S), 256, 0, stream>>>(
      Adjb, f1t, nullptr, nullptr, 0, kSIZE, 256, kITEMS, kITEMS + kOUTF,
      nullptr, 0, kITEMS / S, partK);
  if (S > 1)
    reducek_kernel<<<kSIZE * 256 / 4 / 256, 256, 0, stream>>>(partK, x1f, kSIZE * 256 / 4, S);

  // ---- 4) GNN layers 1 & 2 ----
  const ushort_t* curb[3] = {hLb, hDb, hMb};
  for (int layer = 0; layer < 2; ++layer) {
    int K = (layer == 0) ? kFEAT : kHID;
    const ushort_t* WtL = (layer == 0) ? WLt : WL2t;
    const ushort_t* WtD = (layer == 0) ? WDt : WD2t;
    const ushort_t* WtM = (layer == 0) ? WMt : WM2t;
    const float* bl = Bb[layer];
    ZDescs zd;
    zd.d[0] = {curb[0], WtL, zL, dsc(0), dsc(4),  kNL, K};
    zd.d[1] = {curb[1], WtD, zD, dsc(2), dsc(8),  kND, K};
    zd.d[2] = {curb[2], WtM, zM, dsc(6), dsc(10), kNM, K};
    zgemm_batched_kernel<<<dim3(1, kNL / 128, 3), 256, 0, stream>>>(zd);
    GDescs gd;
    // oL <- t1 (zD cols 0-63) + t3 (zM cols 0-63)
    gd.d[0] = {zD, rp_all + rpo.v[1], csr + (size_t)1 * kE, dsc(3),
               zM, rp_all + rpo.v[3], csr + (size_t)3 * kE, dsc(7),
               bl + 1 * kHID, bl + 3 * kHID, aLb, kNL};
    // oD <- t0 (zL cols 0-63) + t5 (zM cols 64-127)
    gd.d[1] = {zL, rp_all + rpo.v[0], csr + (size_t)0 * kE, dsc(1),
               zM + 64, rp_all + rpo.v[5], csr + (size_t)5 * kE, dsc(11),
               bl + 0 * kHID, bl + 5 * kHID, aDb, kND};
    // oM <- t2 (zL cols 64-127) + t4 (zD cols 64-127)
    gd.d[2] = {zL + 64, rp_all + rpo.v[2], csr + (size_t)2 * kE, dsc(5),
               zD + 64, rp_all + rpo.v[4], csr + (size_t)4 * kE, dsc(9),
               bl + 2 * kHID, bl + 4 * kHID, aMb, kNM};
    gather_batched_kernel<<<dim3(kNL / 4, 1, 3), 256, 0, stream>>>(gd);
    curb[0] = aLb; curb[1] = aDb; curb[2] = aMb;
  }

  // ---- 5) layer 3 (types 1: D->L, 3: M->L; rows < 2048) + L1 norm ----
  float* emb  = (float*)d_out;
  float* outx = (float*)d_out + (size_t)kSIZE * kOUTF;
  {
    ZDescs zd;
    zd.d[0] = {curb[1], W3t1, zD3, dsc(2), dsc(2), kND, kHID};
    zd.d[1] = {curb[2], W3t3, zM3, dsc(6), dsc(6), kNM, kHID};
    zd.d[2] = zd.d[1];
    zgemm_batched_kernel<<<dim3(1, kND / 128, 2), 256, 0, stream>>>(zd);
    gather128_l1_kernel<<<kSIZE / 4, 256, 0, stream>>>(
        zD3, rp_all + rpo.v[1], csr + (size_t)1 * kE, dsc(3),
        zM3, rp_all + rpo.v[3], csr + (size_t)3 * kE, dsc(7),
        Bb[2] + 1 * kOUTF, Bb[2] + 3 * kOUTF, emb, embb);
  }

  // ---- 6) MLP ----
  gemm_bf16_kernel<<<dim3(2, 16, 1), 256, 0, stream>>>(
      embb, f1t + kITEMS, x1f, x1b, 1, kSIZE, 256, kOUTF, kITEMS + kOUTF,
      f1_b, 1, 0, nullptr);
  gemm_bf16_kernel<<<dim3(4, 16, 1), 256, 0, stream>>>(
      x1b, f2t, nullptr, x2b, 1, kSIZE, 512, 256, 256, f2_b, 1, 0, nullptr);
  gemm_bf16_kernel<<<dim3(8, 16, 1), 256, 0, stream>>>(
      x2b, f3t, nullptr, x3b, 1, kSIZE, 1024, 512, 512, f3_b, 1, 0, nullptr);
  gemm_bf16_kernel<<<dim3(32, 16, 1), 256, 0, stream>>>(
      x3b, f4t, nullptr, outx, 0, kSIZE, kITEMS, 1024, 1024, f4_b, 2, 0, nullptr);
}

// Round 8
// 412.976 us; speedup vs baseline: 1.0424x; 1.0346x over previous
//
#include <hip/hip_runtime.h>

constexpr int kNL = 16384, kND = 4096, kNM = 2048;
constexpr int kE = 262144;              // 2^18
constexpr int kFEAT = 256, kHID = 64, kOUTF = 128;
constexpr int kITEMS = 4096, kSIZE = 2048;
constexpr int kHB = 16;                 // histogram chunks per index array
constexpr int kZS = 128;                // z row stride (merged 2-type layout)

typedef unsigned short ushort_t;
typedef unsigned int uint_t;
typedef __attribute__((ext_vector_type(8))) short short8v;
typedef __attribute__((ext_vector_type(4))) float f32x4;

struct EdgePtrs { const int* p[12]; };
struct I6 { int v[6]; };

__device__ inline ushort_t f2bf(float f) {
  unsigned u = __builtin_bit_cast(unsigned, f);
  unsigned r = u + 0x7fffu + ((u >> 16) & 1u);
  return (ushort_t)(r >> 16);
}
__device__ inline float bf2f(ushort_t b) {
  unsigned u = ((unsigned)b) << 16;
  return __builtin_bit_cast(float, u);
}

// async global->LDS, 16 B per lane (global_load_lds_dwordx4)
__device__ __forceinline__ void gload16(const ushort_t* g, ushort_t* l) {
  __builtin_amdgcn_global_load_lds(
      (const __attribute__((address_space(1))) void*)g,
      (__attribute__((address_space(3))) void*)l, 16, 0, 0);
}

// bijective XCD swizzle (m204), y-fastest orientation for L2 panel locality
__device__ __forceinline__ void xcd_swizzle(int& bx, int& by) {
  int gx = gridDim.x, gy = gridDim.y;
  int nwg = gx * gy;
  int orig = by * gx + bx;
  int q = nwg >> 3, r = nwg & 7;
  int xcd = orig & 7, loc = orig >> 3;
  int s = ((xcd < r) ? xcd * (q + 1) : r * (q + 1) + (xcd - r) * q) + loc;
  by = s % gy;
  bx = s / gy;
}

// ===== prep: all fp32->bf16 converts + transpose-converts in ONE launch ====
struct PJob { const float* in; ushort_t* out; int A; int B; int kind; int nblk; };
struct PJobs { PJob j[24]; int n; };

__global__ __launch_bounds__(256) void prep_kernel(PJobs jobs) {
  __shared__ float t[32][33];
  int b = blockIdx.x;
  int ji = 0;
  while (ji < jobs.n && b >= jobs.j[ji].nblk) { b -= jobs.j[ji].nblk; ++ji; }
  if (ji >= jobs.n) return;
  PJob jb = jobs.j[ji];
  if (jb.kind == 0) {                       // flat convert, A = n4
    int idx = b * 256 + threadIdx.x;
    if (idx >= jb.A) return;
    float4 v = ((const float4*)jb.in)[idx];
    ushort_t* o = jb.out + (size_t)idx * 4;
    o[0] = f2bf(v.x); o[1] = f2bf(v.y); o[2] = f2bf(v.z); o[3] = f2bf(v.w);
  } else {                                  // transpose: in [K][N] -> out [N][K]; A=K, B=N
    int K = jb.A, N = jb.B;
    int tpr = N >> 5;
    int n0 = (b % tpr) * 32, k0 = (b / tpr) * 32;
    int tx = threadIdx.x & 31, ty = threadIdx.x >> 5;
#pragma unroll
    for (int i = 0; i < 32; i += 8)
      t[ty + i][tx] = jb.in[(size_t)(k0 + ty + i) * N + n0 + tx];
    __syncthreads();
#pragma unroll
    for (int i = 0; i < 32; i += 8)
      jb.out[(size_t)(n0 + ty + i) * K + k0 + tx] = f2bf(t[tx][ty + i]);
  }
}

// ===== degree/CSR build (no global atomics) ================================
__global__ __launch_bounds__(256) void hist_kernel(EdgePtrs ep, uint_t* __restrict__ part) {
  __shared__ uint_t bins[16384];
  int k = blockIdx.x >> 4, chunk = blockIdx.x & (kHB - 1);
  for (int i = threadIdx.x; i < 16384; i += 256) bins[i] = 0;
  __syncthreads();
  const int* arr = ep.p[k];
  int base = chunk * (kE / kHB);
  for (int i = threadIdx.x; i < kE / kHB; i += 256)
    atomicAdd(&bins[arr[base + i]], 1u);
  __syncthreads();
  uint_t* o = part + ((size_t)blockIdx.x << 14);
  for (int i = threadIdx.x; i < 16384; i += 256) o[i] = bins[i];
}

__global__ void reduce_finalize_kernel(const uint_t* __restrict__ part,
                                       uint_t* __restrict__ cnts,
                                       float* __restrict__ degscale) {
  int idx = blockIdx.x * 256 + threadIdx.x;   // grid = 12*16384/256
  int k = idx >> 14, bin = idx & 16383;
  uint_t s = 0;
  for (int c = 0; c < kHB; ++c) s += part[((size_t)(k * kHB + c) << 14) + bin];
  cnts[idx] = s;
  degscale[idx] = rsqrtf((float)max(s, 1u));
}

__global__ __launch_bounds__(1024) void scan_kernel(const uint_t* __restrict__ cnts,
                                                    uint_t* __restrict__ rp_all,
                                                    I6 rpoff, I6 nd) {
  __shared__ uint_t sums[1024];
  int t = blockIdx.x;
  int n = nd.v[t];
  const uint_t* c = cnts + ((size_t)(2 * t + 1) << 14);
  uint_t* rp = rp_all + rpoff.v[t];
  int tid = threadIdx.x;
  int seg = n >> 10;
  uint_t s = 0;
  for (int j = 0; j < seg; ++j) s += c[tid * seg + j];
  sums[tid] = s;
  __syncthreads();
  for (int o = 1; o < 1024; o <<= 1) {
    uint_t v = (tid >= o) ? sums[tid - o] : 0u;
    __syncthreads();
    sums[tid] += v;
    __syncthreads();
  }
  uint_t run = sums[tid] - s;   // exclusive
  for (int j = 0; j < seg; ++j) { rp[tid * seg + j] = run; run += c[tid * seg + j]; }
  if (tid == 1023) rp[n] = run;
}

__global__ void chunkofs_kernel(const uint_t* __restrict__ part,
                                const uint_t* __restrict__ rp_all,
                                I6 rpoff, I6 nd, uint_t* __restrict__ ofs) {
  int idx = blockIdx.x * 256 + threadIdx.x;   // grid = 6*16384/256
  int t = idx >> 14, bin = idx & 16383;
  if (bin >= nd.v[t]) return;
  uint_t run = (rp_all + rpoff.v[t])[bin];
  for (int c = 0; c < kHB; ++c) {
    ofs[((size_t)(t * kHB + c) << 14) + bin] = run;
    run += part[((size_t)((2 * t + 1) * kHB + c) << 14) + bin];
  }
}

__global__ __launch_bounds__(256) void fill_kernel(EdgePtrs ep,
                                                   const uint_t* __restrict__ ofs,
                                                   uint_t* __restrict__ csr_all) {
  __shared__ uint_t cursor[16384];
  int t = blockIdx.x >> 4, chunk = blockIdx.x & (kHB - 1);
  const uint_t* o = ofs + ((size_t)(t * kHB + chunk) << 14);
  for (int i = threadIdx.x; i < 16384; i += 256) cursor[i] = o[i];
  __syncthreads();
  const int* srcp = ep.p[2 * t];
  const int* dstp = ep.p[2 * t + 1];
  int base = chunk * (kE / kHB);
  uint_t* csr = csr_all + (size_t)t * kE;
  for (int i = threadIdx.x; i < kE / kHB; i += 256) {
    int e = base + i;
    int d = dstp[e];
    uint_t pos = atomicAdd(&cursor[d], 1u);
    csr[pos] = (uint_t)srcp[e];
  }
}

// ===== generic bf16 MFMA GEMM, 128x128 tile, BK=64, 2-buffer T3-minimum ====
// LDS rows are 128B (8 x 16B slots); stored slot = logical ^ (row&7) via
// pre-swizzled global source (rule #21); fragment read applies same XOR.
__global__ __launch_bounds__(256) void gemm_bf16_kernel(
    const ushort_t* __restrict__ A, const ushort_t* __restrict__ Bt,
    const float* __restrict__ Cin, void* __restrict__ out, int outBf16,
    int M, int N, int K, int ldb,
    const float* __restrict__ bias, int act,
    int kChunk, float* __restrict__ partOut) {
  __shared__ ushort_t As[2][8192];   // 2 x 16 KB
  __shared__ ushort_t Bs[2][8192];
  int tid = threadIdx.x;
  int wave = tid >> 6, lane = tid & 63;
  int bx = blockIdx.x, by = blockIdx.y;
  xcd_swizzle(bx, by);
  int brow = by * 128, bcol = bx * 128;
  int kStart = partOut ? blockIdx.z * kChunk : 0;
  int kLen = partOut ? kChunk : K;
  int nsteps = kLen >> 6;              // BK = 64

  // staging map: thread covers LDS slots L = j*256+tid (j=0..3), 16B each;
  // row = L>>3 = j*32 + (tid>>3), stored slot s = L&7 = tid&7,
  // logical slot u = s ^ (row&7) -> global col = u*8 elems.
  int rowBase = tid >> 3;              // 0..31
  int u = (tid & 7) ^ (rowBase & 7);
  const ushort_t* gA = A + (size_t)(brow + rowBase) * K + kStart + u * 8;
  const ushort_t* gB = Bt + (size_t)(bcol + rowBase) * ldb + kStart + u * 8;

  int fr = lane & 15, fq = lane >> 4;
  f32x4 acc[2][8] = {};

#define STAGE_G(buf, koff)                                              \
  do {                                                                  \
    _Pragma("unroll")                                                   \
    for (int j = 0; j < 4; ++j) {                                       \
      gload16(gA + (size_t)j * 32 * K + (koff), &As[buf][j * 2048 + tid * 8]);   \
      gload16(gB + (size_t)j * 32 * ldb + (koff), &Bs[buf][j * 2048 + tid * 8]); \
    }                                                                   \
  } while (0)

  STAGE_G(0, 0);
  int cur = 0;
  for (int i = 0; i < nsteps; ++i) {
    __syncthreads();                   // drains stage(i) DMA; fences buffer reuse
    if (i + 1 < nsteps) STAGE_G(cur ^ 1, (i + 1) * 64);
#pragma unroll
    for (int kk = 0; kk < 2; ++kk) {
      short8v af[2], bfr[8];
#pragma unroll
      for (int mi = 0; mi < 2; ++mi) {
        int row = wave * 32 + mi * 16 + fr;
        af[mi] = *(const short8v*)(&As[cur][row * 64 + (((kk * 4 + fq) ^ (row & 7)) * 8)]);
      }
#pragma unroll
      for (int ni = 0; ni < 8; ++ni) {
        int row = ni * 16 + fr;
        bfr[ni] = *(const short8v*)(&Bs[cur][row * 64 + (((kk * 4 + fq) ^ (row & 7)) * 8)]);
      }
#pragma unroll
      for (int mi = 0; mi < 2; ++mi)
#pragma unroll
        for (int ni = 0; ni < 8; ++ni)
          acc[mi][ni] = __builtin_amdgcn_mfma_f32_16x16x32_bf16(af[mi], bfr[ni], acc[mi][ni], 0, 0, 0);
    }
    cur ^= 1;
  }
#undef STAGE_G

  if (partOut) {
    float* o = partOut + (size_t)blockIdx.z * M * N;
#pragma unroll
    for (int mi = 0; mi < 2; ++mi)
#pragma unroll
      for (int ni = 0; ni < 8; ++ni)
#pragma unroll
        for (int r = 0; r < 4; ++r) {
          int row = brow + wave * 32 + mi * 16 + fq * 4 + r;
          int col = bcol + ni * 16 + fr;
          o[(size_t)row * N + col] = acc[mi][ni][r];
        }
    return;
  }
#pragma unroll
  for (int mi = 0; mi < 2; ++mi)
#pragma unroll
    for (int ni = 0; ni < 8; ++ni)
#pragma unroll
      for (int r = 0; r < 4; ++r) {
        int row = brow + wave * 32 + mi * 16 + fq * 4 + r;
        int col = bcol + ni * 16 + fr;
        float v = acc[mi][ni][r];
        if (Cin) v += Cin[(size_t)row * N + col];
        if (bias) v += bias[col];
        if (act == 1) v = fmaxf(v, 0.0f);
        else if (act == 2) v = 1.0f / (1.0f + expf(-v));
        if (outBf16) ((ushort_t*)out)[(size_t)row * N + col] = f2bf(v);
        else ((float*)out)[(size_t)row * N + col] = v;
      }
}

// ===== batched z GEMM: N=128, out = [rs0|rs1] .* (A @ Bt^T), bf16 ==========
struct ZDesc { const ushort_t* A; const ushort_t* Bt; ushort_t* out;
               const float* rs0; const float* rs1; int M; int K; };
struct ZDescs { ZDesc d[3]; };

__global__ __launch_bounds__(256) void zgemm_batched_kernel(ZDescs ds) {
  __shared__ ushort_t As[2][8192];
  __shared__ ushort_t Bs[2][8192];
  ZDesc de = ds.d[blockIdx.z];
  // swizzle y within the slice (spreads active blocks across XCDs)
  int gy = gridDim.y;
  int yq = gy >> 3;
  int ys = (blockIdx.y & 7) * yq + (blockIdx.y >> 3);
  int brow = ys * 128;
  if (brow >= de.M) return;
  int K = de.K;
  int nsteps = K >> 6;                 // BK = 64 (K is 64, 128 or 256)
  if (nsteps == 0) nsteps = 1;         // K == 64 handled below via kk cap
  int kkMax = (K >= 64) ? 2 : 1;
  int tid = threadIdx.x;
  int wave = tid >> 6, lane = tid & 63;

  int rowBase = tid >> 3;
  int u = (tid & 7) ^ (rowBase & 7);
  const ushort_t* gA = de.A + (size_t)(brow + rowBase) * K + u * 8;
  const ushort_t* gB = de.Bt + (size_t)rowBase * K + u * 8;

  int fr = lane & 15, fq = lane >> 4;
  f32x4 acc[2][8] = {};

#define STAGE_Z(buf, koff)                                              \
  do {                                                                  \
    _Pragma("unroll")                                                   \
    for (int j = 0; j < 4; ++j) {                                       \
      gload16(gA + (size_t)j * 32 * K + (koff), &As[buf][j * 2048 + tid * 8]); \
      gload16(gB + (size_t)j * 32 * K + (koff), &Bs[buf][j * 2048 + tid * 8]); \
    }                                                                   \
  } while (0)

  STAGE_Z(0, 0);
  int cur = 0;
  for (int i = 0; i < nsteps; ++i) {
    __syncthreads();
    if (i + 1 < nsteps) STAGE_Z(cur ^ 1, (i + 1) * 64);
#pragma unroll
    for (int kk = 0; kk < 2; ++kk) {
      if (kk >= kkMax) break;
      short8v af[2], bfr[8];
#pragma unroll
      for (int mi = 0; mi < 2; ++mi) {
        int row = wave * 32 + mi * 16 + fr;
        af[mi] = *(const short8v*)(&As[cur][row * 64 + (((kk * 4 + fq) ^ (row & 7)) * 8)]);
      }
#pragma unroll
      for (int ni = 0; ni < 8; ++ni) {
        int row = ni * 16 + fr;
        bfr[ni] = *(const short8v*)(&Bs[cur][row * 64 + (((kk * 4 + fq) ^ (row & 7)) * 8)]);
      }
#pragma unroll
      for (int mi = 0; mi < 2; ++mi)
#pragma unroll
        for (int ni = 0; ni < 8; ++ni)
          acc[mi][ni] = __builtin_amdgcn_mfma_f32_16x16x32_bf16(af[mi], bfr[ni], acc[mi][ni], 0, 0, 0);
    }
    cur ^= 1;
  }
#undef STAGE_Z

#pragma unroll
  for (int mi = 0; mi < 2; ++mi)
#pragma unroll
    for (int ni = 0; ni < 8; ++ni) {
      const float* rs = (ni < 4) ? de.rs0 : de.rs1;
#pragma unroll
      for (int r = 0; r < 4; ++r) {
        int row = brow + wave * 32 + mi * 16 + fq * 4 + r;
        int col = ni * 16 + fr;
        de.out[(size_t)row * 128 + col] = f2bf(acc[mi][ni][r] * rs[row]);
      }
    }
}

// ===== batched CSR gather (width 64, z row stride 128) =====================
struct GDesc { const ushort_t* z0; const uint_t* rp0; const uint_t* cs0; const float* s0;
               const ushort_t* z1; const uint_t* rp1; const uint_t* cs1; const float* s1;
               const float* b0; const float* b1; ushort_t* out; int nd; };
struct GDescs { GDesc d[3]; };

__global__ __launch_bounds__(256) void gather_batched_kernel(GDescs ds) {
  GDesc de = ds.d[blockIdx.z];
  int d = blockIdx.x * 4 + (threadIdx.x >> 6);
  if (d >= de.nd) return;
  int c = threadIdx.x & 63;
  float acc;
  {
    uint_t e = de.rp0[d], ee = de.rp0[d + 1];
    float a0 = 0, a1 = 0, a2 = 0, a3 = 0;
    for (; e + 4 <= ee; e += 4) {
      uint_t s0 = de.cs0[e], s1 = de.cs0[e + 1], s2 = de.cs0[e + 2], s3 = de.cs0[e + 3];
      a0 += bf2f(de.z0[s0 * kZS + c]); a1 += bf2f(de.z0[s1 * kZS + c]);
      a2 += bf2f(de.z0[s2 * kZS + c]); a3 += bf2f(de.z0[s3 * kZS + c]);
    }
    for (; e < ee; ++e) a0 += bf2f(de.z0[de.cs0[e] * kZS + c]);
    acc = (a0 + a1 + a2 + a3) * de.s0[d];
  }
  {
    uint_t e = de.rp1[d], ee = de.rp1[d + 1];
    float a0 = 0, a1 = 0, a2 = 0, a3 = 0;
    for (; e + 4 <= ee; e += 4) {
      uint_t s0 = de.cs1[e], s1 = de.cs1[e + 1], s2 = de.cs1[e + 2], s3 = de.cs1[e + 3];
      a0 += bf2f(de.z1[s0 * kZS + c]); a1 += bf2f(de.z1[s1 * kZS + c]);
      a2 += bf2f(de.z1[s2 * kZS + c]); a3 += bf2f(de.z1[s3 * kZS + c]);
    }
    for (; e < ee; ++e) a0 += bf2f(de.z1[de.cs1[e] * kZS + c]);
    acc += (a0 + a1 + a2 + a3) * de.s1[d];
  }
  acc += de.b0[c] + de.b1[c];
  de.out[(size_t)d * 64 + c] = f2bf(acc);
}

// ===== layer-3 gather (width 128, d<2048) fused with L1 normalize ==========
__global__ __launch_bounds__(256) void gather128_l1_kernel(
    const ushort_t* __restrict__ zD, const uint_t* __restrict__ rpD, const uint_t* __restrict__ csD,
    const float* __restrict__ sInD,
    const ushort_t* __restrict__ zM, const uint_t* __restrict__ rpM, const uint_t* __restrict__ csM,
    const float* __restrict__ sInM,
    const float* __restrict__ bD, const float* __restrict__ bM,
    float* __restrict__ emb, ushort_t* __restrict__ embb) {
  int d = blockIdx.x * 4 + (threadIdx.x >> 6);
  int c = threadIdx.x & 63;
  float v0 = 0, v1 = 0;
  {
    uint_t e = rpD[d], ee = rpD[d + 1];
    float a0 = 0, a1 = 0, h0 = 0, h1 = 0;
    for (; e + 2 <= ee; e += 2) {
      uint_t s0 = csD[e], s1 = csD[e + 1];
      a0 += bf2f(zD[s0 * 128 + c]);      h0 += bf2f(zD[s0 * 128 + 64 + c]);
      a1 += bf2f(zD[s1 * 128 + c]);      h1 += bf2f(zD[s1 * 128 + 64 + c]);
    }
    if (e < ee) { uint_t s = csD[e]; a0 += bf2f(zD[s * 128 + c]); h0 += bf2f(zD[s * 128 + 64 + c]); }
    v0 += (a0 + a1) * sInD[d]; v1 += (h0 + h1) * sInD[d];
  }
  {
    uint_t e = rpM[d], ee = rpM[d + 1];
    float a0 = 0, a1 = 0, h0 = 0, h1 = 0;
    for (; e + 2 <= ee; e += 2) {
      uint_t s0 = csM[e], s1 = csM[e + 1];
      a0 += bf2f(zM[s0 * 128 + c]);      h0 += bf2f(zM[s0 * 128 + 64 + c]);
      a1 += bf2f(zM[s1 * 128 + c]);      h1 += bf2f(zM[s1 * 128 + 64 + c]);
    }
    if (e < ee) { uint_t s = csM[e]; a0 += bf2f(zM[s * 128 + c]); h0 += bf2f(zM[s * 128 + 64 + c]); }
    v0 += (a0 + a1) * sInM[d]; v1 += (h0 + h1) * sInM[d];
  }
  v0 += bD[c] + bM[c];
  v1 += bD[64 + c] + bM[64 + c];
  float a = fabsf(v0) + fabsf(v1);
#pragma unroll
  for (int o = 32; o > 0; o >>= 1) a += __shfl_xor(a, o);
  float l1 = fmaxf(a, 1e-12f);
  float e0 = v0 / l1, e1 = v1 / l1;
  emb[d * kOUTF + c] = e0;
  emb[d * kOUTF + 64 + c] = e1;
  embb[d * kOUTF + c] = f2bf(e0);
  embb[d * kOUTF + 64 + c] = f2bf(e1);
}

// ===== split-K reduce ======================================================
__global__ void reducek_kernel(const float* __restrict__ P, float* __restrict__ out,
                               int n4, int S) {
  int idx = blockIdx.x * 256 + threadIdx.x;
  if (idx >= n4) return;
  float4 a = ((const float4*)P)[idx];
  for (int s = 1; s < S; ++s) {
    float4 b = ((const float4*)P)[(size_t)s * n4 + idx];
    a.x += b.x; a.y += b.y; a.z += b.z; a.w += b.w;
  }
  ((float4*)out)[idx] = a;
}

extern "C" void kernel_launch(void* const* d_in, const int* in_sizes, int n_in,
                              void* d_out, int out_size, void* d_ws, size_t ws_size,
                              hipStream_t stream) {
  const float* h_L = (const float*)d_in[0];
  const float* h_D = (const float*)d_in[1];
  const float* h_M = (const float*)d_in[2];
  const float* Adj = (const float*)d_in[3];
  EdgePtrs ep;
  for (int i = 0; i < 12; ++i) ep.p[i] = (const int*)d_in[4 + i];
  const float* W[3]  = {(const float*)d_in[16], (const float*)d_in[18], (const float*)d_in[20]};
  const float* Bb[3] = {(const float*)d_in[17], (const float*)d_in[19], (const float*)d_in[21]};
  const float* f1_w = (const float*)d_in[22];
  const float* f1_b = (const float*)d_in[23];
  const float* f2_w = (const float*)d_in[24];
  const float* f2_b = (const float*)d_in[25];
  const float* f3_w = (const float*)d_in[26];
  const float* f3_b = (const float*)d_in[27];
  const float* f4_w = (const float*)d_in[28];
  const float* f4_b = (const float*)d_in[29];

  // ---- workspace layout ----
  float* ws = (float*)d_ws;
  size_t off = 0;
  auto allocF = [&](size_t n) { float* p = ws + off; off += (n + 3) & ~(size_t)3; return p; };
  auto allocU = [&](size_t n) { return (uint_t*)allocF(n); };
  auto allocB = [&](size_t n) { return (ushort_t*)allocF((n + 1) / 2); };

  uint_t* part   = allocU((size_t)12 * kHB * 16384);   // 12.6 MB, reused as z bufs
  uint_t* cnts   = allocU((size_t)12 * 16384);
  float*  degscale = allocF((size_t)12 * 16384);
  uint_t* rp_all = allocU(45062 + 2);
  uint_t* ofs    = allocU((size_t)6 * kHB * 16384);
  uint_t* csr    = allocU((size_t)6 * kE);
  float* x1f   = allocF((size_t)kSIZE * 256);
  ushort_t* hLb  = allocB((size_t)kNL * kFEAT);
  ushort_t* hDb  = allocB((size_t)kND * kFEAT);
  ushort_t* hMb  = allocB((size_t)kNM * kFEAT);
  ushort_t* Adjb = allocB((size_t)kSIZE * kITEMS);
  ushort_t* aLb  = allocB((size_t)kNL * kHID);
  ushort_t* aDb  = allocB((size_t)kND * kHID);
  ushort_t* aMb  = allocB((size_t)kNM * kHID);
  ushort_t* WLt  = allocB((size_t)128 * kFEAT);   // layer1 [W0;W2]^T
  ushort_t* WDt  = allocB((size_t)128 * kFEAT);   // [W1;W4]^T
  ushort_t* WMt  = allocB((size_t)128 * kFEAT);   // [W3;W5]^T
  ushort_t* WL2t = allocB((size_t)128 * kHID);
  ushort_t* WD2t = allocB((size_t)128 * kHID);
  ushort_t* WM2t = allocB((size_t)128 * kHID);
  ushort_t* W3t1 = allocB((size_t)kOUTF * kHID);
  ushort_t* W3t3 = allocB((size_t)kOUTF * kHID);
  ushort_t* f1t  = allocB((size_t)256 * (kITEMS + kOUTF));
  ushort_t* f2t  = allocB((size_t)512 * 256);
  ushort_t* f3t  = allocB((size_t)1024 * 512);
  ushort_t* f4t  = allocB((size_t)kITEMS * 1024);
  ushort_t* embb = allocB((size_t)kSIZE * kOUTF);
  ushort_t* x1b  = allocB((size_t)kSIZE * 256);
  ushort_t* x2b  = allocB((size_t)kSIZE * 512);
  ushort_t* x3b  = allocB((size_t)kSIZE * 1024);

  // split-K partials if workspace allows
  int S = 1;
  float* partK = x1f;
  if ((off + (size_t)8 * kSIZE * 256 + 16) * 4 <= ws_size) {
    S = 8;
    partK = allocF((size_t)8 * kSIZE * 256);
  }

  // z buffers alias `part` (dead after chunkofs/fill)
  ushort_t* zL  = (ushort_t*)part;                       // 16384 x 128
  ushort_t* zD  = zL + (size_t)kNL * kZS;                // 4096 x 128
  ushort_t* zM  = zD + (size_t)kND * kZS;                // 2048 x 128
  ushort_t* zD3 = zM + (size_t)kNM * kZS;                // 4096 x 128
  ushort_t* zM3 = zD3 + (size_t)kND * kZS;               // 2048 x 128

  I6 ndI; const int ndst_[6] = {kND, kNL, kNM, kNL, kNM, kND};
  for (int t = 0; t < 6; ++t) ndI.v[t] = ndst_[t];
  I6 rpo; { int r = 0; for (int t = 0; t < 6; ++t) { rpo.v[t] = r; r += ndst_[t] + 1; } }
  auto dsc = [&](int k) { return degscale + ((size_t)k << 14); };

  // ---- 1) one prep launch: converts + all weight transposes ----
  PJobs pj; int nj = 0; int totblk = 0;
  auto addCvt = [&](const float* in, ushort_t* out, size_t n) {
    int n4 = (int)(n / 4);
    pj.j[nj] = {in, out, n4, 0, 0, (n4 + 255) / 256}; totblk += pj.j[nj].nblk; ++nj;
  };
  auto addT = [&](const float* in, ushort_t* out, int K, int N) {
    pj.j[nj] = {in, out, K, N, 1, (N / 32) * (K / 32)}; totblk += pj.j[nj].nblk; ++nj;
  };
  addCvt(h_L, hLb, (size_t)kNL * kFEAT);
  addCvt(h_D, hDb, (size_t)kND * kFEAT);
  addCvt(h_M, hMb, (size_t)kNM * kFEAT);
  addCvt(Adj, Adjb, (size_t)kSIZE * kITEMS);
  // layer1 merged weights (K=256, each slice 64 rows)
  addT(W[0] + (size_t)0 * kFEAT * kHID, WLt + (size_t)0 * kFEAT, kFEAT, kHID);
  addT(W[0] + (size_t)2 * kFEAT * kHID, WLt + (size_t)64 * kFEAT, kFEAT, kHID);
  addT(W[0] + (size_t)1 * kFEAT * kHID, WDt + (size_t)0 * kFEAT, kFEAT, kHID);
  addT(W[0] + (size_t)4 * kFEAT * kHID, WDt + (size_t)64 * kFEAT, kFEAT, kHID);
  addT(W[0] + (size_t)3 * kFEAT * kHID, WMt + (size_t)0 * kFEAT, kFEAT, kHID);
  addT(W[0] + (size_t)5 * kFEAT * kHID, WMt + (size_t)64 * kFEAT, kFEAT, kHID);
  // layer2 merged weights (K=64)
  addT(W[1] + (size_t)0 * kHID * kHID, WL2t + (size_t)0 * kHID, kHID, kHID);
  addT(W[1] + (size_t)2 * kHID * kHID, WL2t + (size_t)64 * kHID, kHID, kHID);
  addT(W[1] + (size_t)1 * kHID * kHID, WD2t + (size_t)0 * kHID, kHID, kHID);
  addT(W[1] + (size_t)4 * kHID * kHID, WD2t + (size_t)64 * kHID, kHID, kHID);
  addT(W[1] + (size_t)3 * kHID * kHID, WM2t + (size_t)0 * kHID, kHID, kHID);
  addT(W[1] + (size_t)5 * kHID * kHID, WM2t + (size_t)64 * kHID, kHID, kHID);
  // layer3: only types 1, 3 (N=128)
  addT(W[2] + (size_t)1 * kHID * kOUTF, W3t1, kHID, kOUTF);
  addT(W[2] + (size_t)3 * kHID * kOUTF, W3t3, kHID, kOUTF);
  // MLP weights
  addT(f1_w, f1t, kITEMS + kOUTF, 256);
  addT(f2_w, f2t, 256, 512);
  addT(f3_w, f3t, 512, 1024);
  addT(f4_w, f4t, 1024, kITEMS);
  pj.n = nj;
  prep_kernel<<<totblk, 256, 0, stream>>>(pj);

  // ---- 2) degree + CSR build ----
  hist_kernel<<<12 * kHB, 256, 0, stream>>>(ep, part);
  reduce_finalize_kernel<<<12 * 16384 / 256, 256, 0, stream>>>(part, cnts, degscale);
  scan_kernel<<<6, 1024, 0, stream>>>(cnts, rp_all, rpo, ndI);
  chunkofs_kernel<<<6 * 16384 / 256, 256, 0, stream>>>(part, rp_all, rpo, ndI, ofs);
  fill_kernel<<<6 * kHB, 256, 0, stream>>>(ep, ofs, csr);

  // ---- 3) Adj @ f1_w[:4096] with split-K ----
  gemm_bf16_kernel<<<dim3(2, 16, S), 256, 0, stream>>>(
      Adjb, f1t, nullptr, nullptr, 0, kSIZE, 256, kITEMS, kITEMS + kOUTF,
      nullptr, 0, kITEMS / S, partK);
  if (S > 1)
    reducek_kernel<<<kSIZE * 256 / 4 / 256, 256, 0, stream>>>(partK, x1f, kSIZE * 256 / 4, S);

  // ---- 4) GNN layers 1 & 2 ----
  const ushort_t* curb[3] = {hLb, hDb, hMb};
  for (int layer = 0; layer < 2; ++layer) {
    int K = (layer == 0) ? kFEAT : kHID;
    const ushort_t* WtL = (layer == 0) ? WLt : WL2t;
    const ushort_t* WtD = (layer == 0) ? WDt : WD2t;
    const ushort_t* WtM = (layer == 0) ? WMt : WM2t;
    const float* bl = Bb[layer];
    ZDescs zd;
    zd.d[0] = {curb[0], WtL, zL, dsc(0), dsc(4),  kNL, K};
    zd.d[1] = {curb[1], WtD, zD, dsc(2), dsc(8),  kND, K};
    zd.d[2] = {curb[2], WtM, zM, dsc(6), dsc(10), kNM, K};
    zgemm_batched_kernel<<<dim3(1, kNL / 128, 3), 256, 0, stream>>>(zd);
    GDescs gd;
    // oL <- t1 (zD cols 0-63) + t3 (zM cols 0-63)
    gd.d[0] = {zD, rp_all + rpo.v[1], csr + (size_t)1 * kE, dsc(3),
               zM, rp_all + rpo.v[3], csr + (size_t)3 * kE, dsc(7),
               bl + 1 * kHID, bl + 3 * kHID, aLb, kNL};
    // oD <- t0 (zL cols 0-63) + t5 (zM cols 64-127)
    gd.d[1] = {zL, rp_all + rpo.v[0], csr + (size_t)0 * kE, dsc(1),
               zM + 64, rp_all + rpo.v[5], csr + (size_t)5 * kE, dsc(11),
               bl + 0 * kHID, bl + 5 * kHID, aDb, kND};
    // oM <- t2 (zL cols 64-127) + t4 (zD cols 64-127)
    gd.d[2] = {zL + 64, rp_all + rpo.v[2], csr + (size_t)2 * kE, dsc(5),
               zD + 64, rp_all + rpo.v[4], csr + (size_t)4 * kE, dsc(9),
               bl + 2 * kHID, bl + 4 * kHID, aMb, kNM};
    gather_batched_kernel<<<dim3(kNL / 4, 1, 3), 256, 0, stream>>>(gd);
    curb[0] = aLb; curb[1] = aDb; curb[2] = aMb;
  }

  // ---- 5) layer 3 (types 1: D->L, 3: M->L; rows < 2048) + L1 norm ----
  float* emb  = (float*)d_out;
  float* outx = (float*)d_out + (size_t)kSIZE * kOUTF;
  {
    ZDescs zd;
    zd.d[0] = {curb[1], W3t1, zD3, dsc(2), dsc(2), kND, kHID};
    zd.d[1] = {curb[2], W3t3, zM3, dsc(6), dsc(6), kNM, kHID};
    zd.d[2] = zd.d[1];
    zgemm_batched_kernel<<<dim3(1, kND / 128, 2), 256, 0, stream>>>(zd);
    gather128_l1_kernel<<<kSIZE / 4, 256, 0, stream>>>(
        zD3, rp_all + rpo.v[1], csr + (size_t)1 * kE, dsc(3),
        zM3, rp_all + rpo.v[3], csr + (size_t)3 * kE, dsc(7),
        Bb[2] + 1 * kOUTF, Bb[2] + 3 * kOUTF, emb, embb);
  }

  // ---- 6) MLP ----
  gemm_bf16_kernel<<<dim3(2, 16, 1), 256, 0, stream>>>(
      embb, f1t + kITEMS, x1f, x1b, 1, kSIZE, 256, kOUTF, kITEMS + kOUTF,
      f1_b, 1, 0, nullptr);
  gemm_bf16_kernel<<<dim3(4, 16, 1), 256, 0, stream>>>(
      x1b, f2t, nullptr, x2b, 1, kSIZE, 512, 256, 256, f2_b, 1, 0, nullptr);
  gemm_bf16_kernel<<<dim3(8, 16, 1), 256, 0, stream>>>(
      x2b, f3t, nullptr, x3b, 1, kSIZE, 1024, 512, 512, f3_b, 1, 0, nullptr);
  gemm_bf16_kernel<<<dim3(32, 16, 1), 256, 0, stream>>>(
      x3b, f4t, nullptr, outx, 0, kSIZE, kITEMS, 1024, 1024, f4_b, 2, 0, nullptr);
}